// Round 2
// baseline (1575.049 us; speedup 1.0000x reference)
//
#include <hip/hip_runtime.h>
#include <cstdint>
#include <cstddef>

// Mamba backbone fwd: B=4, L=4096, IN=256, DM=512, DI=1024, N=16, R=32.
// Round 1: fp32 baseline, workspace shrunk to ~231 MB via buffer aliasing
// (suspected ws_size overflow caused round-0 abort).
// Output mean trick: mean_t(y_t) @ out_w == (mean_t y_t) @ out_w.

#define B_    4
#define L_    4096
#define M_    (B_ * L_)        // 16384 rows
#define DIN   256
#define DM    512
#define DI    1024
#define NS    16
#define RK    32
#define XD    64               // RK + 2*NS
#define TCH   128              // scan chunk length
#define NCH   (L_ / TCH)       // 32 chunks
#define NCHAN (B_ * DI)        // 4096 scalar channels (x16 states each)

// ------ generic tiled fp32 GEMM: C[M,N](ldc) = A[M,K] @ W[K,N](ldw) + bias --
// 64x64 block tile, 256 threads, 4x4 per thread, BK=16.
__global__ __launch_bounds__(256) void gemm_f32(
    const float* __restrict__ A, const float* __restrict__ W,
    const float* __restrict__ bias, float* __restrict__ C,
    int M, int N, int K, int ldw, int ldc)
{
  __shared__ float As[16][64];   // [k][m]
  __shared__ float Bs[16][64];   // [k][n]
  const int tid = threadIdx.x;
  const int bm0 = blockIdx.y * 64;
  const int bn0 = blockIdx.x * 64;
  const int tm = (tid >> 4) << 2;   // 0,4,8,12
  const int tn = (tid & 15) << 2;   // 0..60
  const int am = tid >> 2;          // 0..63   (A-load row)
  const int ak = (tid & 3) << 2;    // 0,4,8,12 (A-load k)
  const int bk = tid >> 4;          // 0..15   (B-load k)
  const int bn = (tid & 15) << 2;   // 0..60   (B-load n)
  float acc[4][4] = {};
  for (int k0 = 0; k0 < K; k0 += 16) {
    float4 av = *(const float4*)(A + (size_t)(bm0 + am) * K + k0 + ak);
    As[ak + 0][am] = av.x; As[ak + 1][am] = av.y;
    As[ak + 2][am] = av.z; As[ak + 3][am] = av.w;
    float4 bv = *(const float4*)(W + (size_t)(k0 + bk) * ldw + bn0 + bn);
    *(float4*)&Bs[bk][bn] = bv;
    __syncthreads();
#pragma unroll
    for (int k = 0; k < 16; ++k) {
      float4 a4 = *(const float4*)&As[k][tm];
      float4 b4 = *(const float4*)&Bs[k][tn];
      float aa[4] = {a4.x, a4.y, a4.z, a4.w};
      float bb[4] = {b4.x, b4.y, b4.z, b4.w};
#pragma unroll
      for (int i = 0; i < 4; ++i)
#pragma unroll
        for (int j = 0; j < 4; ++j) acc[i][j] += aa[i] * bb[j];
    }
    __syncthreads();
  }
  float bb[4] = {0.f, 0.f, 0.f, 0.f};
  if (bias) {
    float4 b4 = *(const float4*)(bias + bn0 + tn);
    bb[0] = b4.x; bb[1] = b4.y; bb[2] = b4.z; bb[3] = b4.w;
  }
#pragma unroll
  for (int i = 0; i < 4; ++i) {
    float4 o;
    o.x = acc[i][0] + bb[0]; o.y = acc[i][1] + bb[1];
    o.z = acc[i][2] + bb[2]; o.w = acc[i][3] + bb[3];
    *(float4*)(C + (size_t)(bm0 + tm + i) * ldc + bn0 + tn) = o;
  }
}

// ---------------- depthwise causal conv1d (4 taps) + silu --------------------
__global__ __launch_bounds__(256) void conv_silu(
    const float* __restrict__ u, const float* __restrict__ cw,
    const float* __restrict__ cb, float* __restrict__ uc)
{
  int idx = blockIdx.x * 256 + threadIdx.x;   // M_*DI threads
  int e = idx & (DI - 1);
  int m = idx >> 10;
  int t = m & (L_ - 1);
  const float* w = cw + e * 4;
  float acc = cb[e];
#pragma unroll
  for (int k = 0; k < 4; ++k) {
    int tt = t - 3 + k;
    if (tt >= 0) acc += u[(size_t)(m - 3 + k) * DI + e] * w[k];
  }
  uc[idx] = acc * (1.f / (1.f + expf(-acc)));   // silu
}

// ---------------- x_proj: xdbl[M,64] = uc[M,1024] @ xw[1024,64] --------------
__global__ __launch_bounds__(256) void xproj_k(
    const float* __restrict__ uc, const float* __restrict__ xw,
    float* __restrict__ xdbl)
{
  int n = threadIdx.x;                         // 0..63
  int m = blockIdx.x * 4 + threadIdx.y;
  const float* ur = uc + (size_t)m * DI;
  float acc = 0.f;
  for (int k = 0; k < DI; k += 4) {
    float4 u4 = *(const float4*)(ur + k);
    acc += u4.x * xw[(k + 0) * XD + n] + u4.y * xw[(k + 1) * XD + n]
         + u4.z * xw[(k + 2) * XD + n] + u4.w * xw[(k + 3) * XD + n];
  }
  xdbl[(size_t)m * XD + n] = acc;
}

// ---------------- dt_proj + softplus: dtv[M,DI] ------------------------------
__global__ __launch_bounds__(256) void dtproj_k(
    const float* __restrict__ xdbl, const float* __restrict__ dtw,
    const float* __restrict__ dtb, float* __restrict__ dtv)
{
  int idx = blockIdx.x * 256 + threadIdx.x;    // M_*DI threads
  int e = idx & (DI - 1);
  int m = idx >> 10;
  const float* xr = xdbl + (size_t)m * XD;
  float acc = dtb[e];
#pragma unroll
  for (int k = 0; k < RK; ++k) acc += xr[k] * dtw[k * DI + e];
  // softplus = max(x,0) + log1p(exp(-|x|))
  dtv[idx] = fmaxf(acc, 0.f) + log1pf(expf(-fabsf(acc)));
}

// ---------------- scan pass 1: per-chunk decay product P and local state H ---
__global__ __launch_bounds__(256) void scan_pass1(
    const float* __restrict__ dtv, const float* __restrict__ uc,
    const float* __restrict__ xdbl, const float* __restrict__ A_log,
    float* __restrict__ Pbuf, float* __restrict__ Hbuf)
{
  int idx = blockIdx.x * 256 + threadIdx.x;    // NCHAN*NCH threads
  int chan = idx & (NCHAN - 1);
  int chunk = idx >> 12;
  int e = chan & (DI - 1);
  int b = chan >> 10;
  float Ae[NS];
#pragma unroll
  for (int n = 0; n < NS; ++n) Ae[n] = -expf(A_log[e * NS + n]);
  float h[NS], P[NS];
#pragma unroll
  for (int n = 0; n < NS; ++n) { h[n] = 0.f; P[n] = 1.f; }
  int m0 = b * L_ + chunk * TCH;
  for (int t = 0; t < TCH; ++t) {
    size_t m = (size_t)(m0 + t);
    float a = dtv[m * DI + e];
    float du = a * uc[m * DI + e];
    const float* bp = xdbl + m * XD + RK;
    float bv[NS];
#pragma unroll
    for (int n = 0; n < NS; n += 4) {
      float4 v = *(const float4*)(bp + n);
      bv[n] = v.x; bv[n + 1] = v.y; bv[n + 2] = v.z; bv[n + 3] = v.w;
    }
#pragma unroll
    for (int n = 0; n < NS; ++n) {
      float dA = expf(a * Ae[n]);
      P[n] *= dA;
      h[n] = dA * h[n] + du * bv[n];
    }
  }
  size_t base = (size_t)chunk * NS * NCHAN + chan;
#pragma unroll
  for (int n = 0; n < NS; ++n) {
    Pbuf[base + (size_t)n * NCHAN] = P[n];
    Hbuf[base + (size_t)n * NCHAN] = h[n];
  }
}

// ---------------- scan pass 2: compose chunk boundary states -----------------
__global__ __launch_bounds__(256) void scan_pass2(
    const float* __restrict__ Pbuf, const float* __restrict__ Hbuf,
    float* __restrict__ Hstart)
{
  int chan = blockIdx.x * 256 + threadIdx.x;   // NCHAN threads
  float hp[NS];
#pragma unroll
  for (int n = 0; n < NS; ++n) hp[n] = 0.f;
  for (int c = 0; c < NCH; ++c) {
    size_t base = (size_t)c * NS * NCHAN + chan;
#pragma unroll
    for (int n = 0; n < NS; ++n) {
      size_t o = base + (size_t)n * NCHAN;
      Hstart[o] = hp[n];
      hp[n] = Hbuf[o] + Pbuf[o] * hp[n];
    }
  }
}

// ---------------- scan pass 3: replay + y + gate + time-sum ------------------
__global__ __launch_bounds__(256) void scan_pass3(
    const float* __restrict__ dtv, const float* __restrict__ uc,
    const float* __restrict__ xdbl, const float* __restrict__ A_log,
    const float* __restrict__ Hstart, const float* __restrict__ z,
    const float* __restrict__ Dsk, float* __restrict__ sacc)
{
  int idx = blockIdx.x * 256 + threadIdx.x;    // NCHAN*NCH threads
  int chan = idx & (NCHAN - 1);
  int chunk = idx >> 12;
  int e = chan & (DI - 1);
  int b = chan >> 10;
  float Ae[NS];
#pragma unroll
  for (int n = 0; n < NS; ++n) Ae[n] = -expf(A_log[e * NS + n]);
  float h[NS];
  {
    size_t base = (size_t)chunk * NS * NCHAN + chan;
#pragma unroll
    for (int n = 0; n < NS; ++n) h[n] = Hstart[base + (size_t)n * NCHAN];
  }
  float Dv = Dsk[e];
  float ssum = 0.f;
  int m0 = b * L_ + chunk * TCH;
  for (int t = 0; t < TCH; ++t) {
    size_t m = (size_t)(m0 + t);
    float a = dtv[m * DI + e];
    float uu = uc[m * DI + e];
    float du = a * uu;
    const float* bp = xdbl + m * XD + RK;
    float bv[NS], cv[NS];
#pragma unroll
    for (int n = 0; n < NS; n += 4) {
      float4 v = *(const float4*)(bp + n);
      bv[n] = v.x; bv[n + 1] = v.y; bv[n + 2] = v.z; bv[n + 3] = v.w;
      float4 w = *(const float4*)(bp + NS + n);
      cv[n] = w.x; cv[n + 1] = w.y; cv[n + 2] = w.z; cv[n + 3] = w.w;
    }
    float y = 0.f;
#pragma unroll
    for (int n = 0; n < NS; ++n) {
      float dA = expf(a * Ae[n]);
      h[n] = dA * h[n] + du * bv[n];
      y += h[n] * cv[n];
    }
    float zz = z[m * DI + e];
    float gate = zz * (1.f / (1.f + expf(-zz)));  // silu(z)
    ssum += (y + uu * Dv) * gate;
  }
  atomicAdd(&sacc[chan], ssum);
}

// ---------------- final: out[b,d] = (s[b,:]/L) @ out_w -----------------------
__global__ __launch_bounds__(512) void out_proj_k(
    const float* __restrict__ s, const float* __restrict__ ow,
    float* __restrict__ out)
{
  int b = blockIdx.x;
  int d = threadIdx.x;              // 0..511
  const float* sb = s + b * DI;
  float acc = 0.f;
  for (int e = 0; e < DI; ++e) acc += sb[e] * ow[(size_t)e * DM + d];
  out[b * DM + d] = acc * (1.f / (float)L_);
}

extern "C" void kernel_launch(void* const* d_in, const int* in_sizes, int n_in,
                              void* d_out, int out_size, void* d_ws, size_t ws_size,
                              hipStream_t stream)
{
  const float* x      = (const float*)d_in[0];
  const float* w_proj = (const float*)d_in[1];
  const float* b_proj = (const float*)d_in[2];
  const float* in_w   = (const float*)d_in[3];
  const float* conv_w = (const float*)d_in[4];
  const float* conv_b = (const float*)d_in[5];
  const float* xproj_w= (const float*)d_in[6];
  const float* dt_w   = (const float*)d_in[7];
  const float* dt_b   = (const float*)d_in[8];
  const float* A_log  = (const float*)d_in[9];
  const float* D_skip = (const float*)d_in[10];
  const float* out_w  = (const float*)d_in[11];

  // Workspace layout (~231 MB total) with liveness-based aliasing:
  //   bufA: u (steps 2-3)  -> dtv (steps 5-8)       16.78M f
  //   bufZ: z (steps 2-8)                           16.78M f
  //   bufC: h (steps 1-2)  -> uc (steps 3-8)        16.78M f
  float* ws   = (float*)d_ws;
  float* bufA = ws;                                  // u, later dtv
  float* bufZ = bufA + (size_t)M_ * DI;
  float* bufC = bufZ + (size_t)M_ * DI;              // h, later uc
  float* xdbl = bufC + (size_t)M_ * DI;              // M*64
  float* Pb   = xdbl + (size_t)M_ * XD;
  float* Hb   = Pb   + (size_t)NCH * NS * NCHAN;
  float* Hs   = Hb   + (size_t)NCH * NS * NCHAN;
  float* sacc = Hs   + (size_t)NCH * NS * NCHAN;     // 4096 f

  float* h   = bufC;
  float* u   = bufA;
  float* z   = bufZ;
  float* uc  = bufC;
  float* dtv = bufA;

  // 1. h = x @ w_proj + b_proj                      [M, DM]
  gemm_f32<<<dim3(DM / 64, M_ / 64), 256, 0, stream>>>(
      x, w_proj, b_proj, h, M_, DM, DIN, DM, DM);
  // 2. u = h @ in_w[:, :DI] ; z = h @ in_w[:, DI:]  [M, DI] each
  gemm_f32<<<dim3(DI / 64, M_ / 64), 256, 0, stream>>>(
      h, in_w, nullptr, u, M_, DI, DM, 2 * DI, DI);
  gemm_f32<<<dim3(DI / 64, M_ / 64), 256, 0, stream>>>(
      h, in_w + DI, nullptr, z, M_, DI, DM, 2 * DI, DI);
  // 3. uc = silu(causal_dwconv(u) + conv_b)         (overwrites h region; h dead)
  conv_silu<<<(M_ * DI) / 256, 256, 0, stream>>>(u, conv_w, conv_b, uc);
  // 4. xdbl = uc @ xproj_w   (dt_raw | B | C)
  xproj_k<<<M_ / 4, dim3(64, 4), 0, stream>>>(uc, xproj_w, xdbl);
  // 5. dtv = softplus(dt_raw @ dt_w + dt_b)         (overwrites u; u dead)
  dtproj_k<<<(M_ * DI) / 256, 256, 0, stream>>>(xdbl, dt_w, dt_b, dtv);
  // 6-8. chunked selective scan + gate + time-reduction
  scan_pass1<<<(NCHAN * NCH) / 256, 256, 0, stream>>>(dtv, uc, xdbl, A_log, Pb, Hb);
  scan_pass2<<<NCHAN / 256, 256, 0, stream>>>(Pb, Hb, Hs);
  hipMemsetAsync(sacc, 0, NCHAN * sizeof(float), stream);
  scan_pass3<<<(NCHAN * NCH) / 256, 256, 0, stream>>>(dtv, uc, xdbl, A_log, Hs, z, D_skip, sacc);
  // 9. out = (s/L) @ out_w
  out_proj_k<<<B_, DM, 0, stream>>>(sacc, out_w, (float*)d_out);
}

// Round 3
// 1138.096 us; speedup vs baseline: 1.3839x; 1.3839x over previous
//
#include <hip/hip_runtime.h>
#include <cstdint>
#include <cstddef>

// Mamba backbone fwd: B=4, L=4096, IN=256, DM=512, DI=1024, N=16, R=32.
// Round 3: split-bf16 MFMA GEMMs (hi/lo decomposition, 3 MFMAs per fp32
// product, ~2^-18 rel err) for input_proj / in_proj / x_proj.
// Weights pre-transposed+split once per call. Scan kernels unchanged.

#define B_    4
#define L_    4096
#define M_    (B_ * L_)        // 16384 rows
#define DIN   256
#define DM    512
#define DI    1024
#define NS    16
#define RK    32
#define XD    64               // RK + 2*NS
#define TCH   128              // scan chunk length
#define NCH   (L_ / TCH)       // 32 chunks
#define NCHAN (B_ * DI)        // 4096 scalar channels

typedef __bf16 bf16_t;
typedef bf16_t bf16x8 __attribute__((ext_vector_type(8)));
typedef float  f32x4  __attribute__((ext_vector_type(4)));

static __device__ __forceinline__ unsigned short f32_to_bf16_rne(float f) {
  unsigned u = __float_as_uint(f);
  u += 0x7fffu + ((u >> 16) & 1u);       // round-to-nearest-even on magnitude
  return (unsigned short)(u >> 16);
}
static __device__ __forceinline__ float bf16_to_f32(unsigned short h) {
  return __uint_as_float(((unsigned)h) << 16);
}

// ---- weight prep: W[K][N] fp32 -> WT_hi[N][K], WT_lo[N][K] bf16 ------------
__global__ __launch_bounds__(256) void transpose_split(
    const float* __restrict__ W, int K, int N,
    unsigned short* __restrict__ Thi, unsigned short* __restrict__ Tlo)
{
  int idx = blockIdx.x * 256 + threadIdx.x;
  if (idx >= K * N) return;
  int k = idx % K, n = idx / K;          // writes coalesced along k
  float f = W[(size_t)k * N + n];
  unsigned short hi = f32_to_bf16_rne(f);
  float r = f - bf16_to_f32(hi);
  unsigned short lo = f32_to_bf16_rne(r);
  Thi[(size_t)n * K + k] = hi;
  Tlo[(size_t)n * K + k] = lo;
}

// ---- split-bf16 MFMA GEMM: C[M,N] = A[M,K]fp32 x WT[N,K](hi/lo) (+bias) ----
// 256 threads = 4 waves. Wave tile WMxWN of 16x16x32 mfmas, 3 mfma per tile
// (hi*hi + hi*lo + lo*hi). LDS rows padded to 40 elems (80B) -> <=2-way
// conflicts on ds_read_b128 frags.
template<int BM, int BN, int WM, int WN>
__global__ __launch_bounds__(256) void gemm_split(
    const float* __restrict__ A, const unsigned short* __restrict__ Bhi,
    const unsigned short* __restrict__ Blo, const float* __restrict__ bias,
    float* __restrict__ C, int M, int N, int K, int ldc)
{
  constexpr int BK = 32, PAD = 40;
  constexpr int MT = WM / 16, NT = WN / 16;
  constexpr int WCOLS = BN / WN;
  __shared__ unsigned short lAhi[BM * PAD];
  __shared__ unsigned short lAlo[BM * PAD];
  __shared__ unsigned short lBhi[BN * PAD];
  __shared__ unsigned short lBlo[BN * PAD];

  const int tid  = threadIdx.x;
  const int wave = tid >> 6, lane = tid & 63;
  const int wm0 = (wave / WCOLS) * WM, wn0 = (wave % WCOLS) * WN;
  const int bm0 = blockIdx.y * BM, bn0 = blockIdx.x * BN;
  const int sr = tid >> 3;               // 0..31 staging row
  const int sc = (tid & 7) << 2;         // 0,4,...,28 staging k
  const int fm = lane & 15, fq = lane >> 4;

  f32x4 acc[MT][NT];
#pragma unroll
  for (int i = 0; i < MT; ++i)
#pragma unroll
    for (int j = 0; j < NT; ++j) acc[i][j] = 0.f;

  for (int k0 = 0; k0 < K; k0 += BK) {
    // stage A: fp32 -> (hi,lo) bf16
#pragma unroll
    for (int r = sr; r < BM; r += 32) {
      float4 v = *(const float4*)(A + (size_t)(bm0 + r) * K + k0 + sc);
      unsigned short h0 = f32_to_bf16_rne(v.x), h1 = f32_to_bf16_rne(v.y);
      unsigned short h2 = f32_to_bf16_rne(v.z), h3 = f32_to_bf16_rne(v.w);
      ushort4 uh = make_ushort4(h0, h1, h2, h3);
      ushort4 ul = make_ushort4(f32_to_bf16_rne(v.x - bf16_to_f32(h0)),
                                f32_to_bf16_rne(v.y - bf16_to_f32(h1)),
                                f32_to_bf16_rne(v.z - bf16_to_f32(h2)),
                                f32_to_bf16_rne(v.w - bf16_to_f32(h3)));
      *(ushort4*)&lAhi[r * PAD + sc] = uh;
      *(ushort4*)&lAlo[r * PAD + sc] = ul;
    }
    // stage B: plain bf16 copy (pre-split)
#pragma unroll
    for (int r = sr; r < BN; r += 32) {
      *(ushort4*)&lBhi[r * PAD + sc] =
          *(const ushort4*)(Bhi + (size_t)(bn0 + r) * K + k0 + sc);
      *(ushort4*)&lBlo[r * PAD + sc] =
          *(const ushort4*)(Blo + (size_t)(bn0 + r) * K + k0 + sc);
    }
    __syncthreads();
    // fragments + MFMA
    bf16x8 ah[MT], al[MT];
#pragma unroll
    for (int i = 0; i < MT; ++i) {
      int row = wm0 + i * 16 + fm;
      ah[i] = *(const bf16x8*)&lAhi[row * PAD + fq * 8];
      al[i] = *(const bf16x8*)&lAlo[row * PAD + fq * 8];
    }
#pragma unroll
    for (int j = 0; j < NT; ++j) {
      int col = wn0 + j * 16 + fm;
      bf16x8 bh = *(const bf16x8*)&lBhi[col * PAD + fq * 8];
      bf16x8 bl = *(const bf16x8*)&lBlo[col * PAD + fq * 8];
#pragma unroll
      for (int i = 0; i < MT; ++i) {
        acc[i][j] = __builtin_amdgcn_mfma_f32_16x16x32_bf16(ah[i], bh, acc[i][j], 0, 0, 0);
        acc[i][j] = __builtin_amdgcn_mfma_f32_16x16x32_bf16(ah[i], bl, acc[i][j], 0, 0, 0);
        acc[i][j] = __builtin_amdgcn_mfma_f32_16x16x32_bf16(al[i], bh, acc[i][j], 0, 0, 0);
      }
    }
    __syncthreads();
  }
  // epilogue: C/D layout col=lane&15, row=quad*4+reg
#pragma unroll
  for (int j = 0; j < NT; ++j) {
    int gc = bn0 + wn0 + j * 16 + fm;
    float bv = bias ? bias[gc] : 0.f;
#pragma unroll
    for (int i = 0; i < MT; ++i) {
      int gr = bm0 + wm0 + i * 16 + fq * 4;
#pragma unroll
      for (int r = 0; r < 4; ++r)
        C[(size_t)(gr + r) * ldc + gc] = acc[i][j][r] + bv;
    }
  }
}

// ---------------- depthwise causal conv1d (4 taps) + silu --------------------
__global__ __launch_bounds__(256) void conv_silu(
    const float* __restrict__ u, const float* __restrict__ cw,
    const float* __restrict__ cb, float* __restrict__ uc)
{
  int idx = blockIdx.x * 256 + threadIdx.x;   // M_*DI threads
  int e = idx & (DI - 1);
  int m = idx >> 10;
  int t = m & (L_ - 1);
  const float* w = cw + e * 4;
  float acc = cb[e];
#pragma unroll
  for (int k = 0; k < 4; ++k) {
    int tt = t - 3 + k;
    if (tt >= 0) acc += u[(size_t)(m - 3 + k) * DI + e] * w[k];
  }
  uc[idx] = acc * (1.f / (1.f + expf(-acc)));   // silu
}

// ---------------- dt_proj + softplus: dtv[M,DI] ------------------------------
__global__ __launch_bounds__(256) void dtproj_k(
    const float* __restrict__ xdbl, const float* __restrict__ dtw,
    const float* __restrict__ dtb, float* __restrict__ dtv)
{
  int idx = blockIdx.x * 256 + threadIdx.x;    // M_*DI threads
  int e = idx & (DI - 1);
  int m = idx >> 10;
  const float* xr = xdbl + (size_t)m * XD;
  float acc = dtb[e];
#pragma unroll
  for (int k = 0; k < RK; ++k) acc += xr[k] * dtw[k * DI + e];
  dtv[idx] = fmaxf(acc, 0.f) + log1pf(expf(-fabsf(acc)));  // softplus
}

// ---------------- scan pass 1: per-chunk decay product P and local state H ---
__global__ __launch_bounds__(256) void scan_pass1(
    const float* __restrict__ dtv, const float* __restrict__ uc,
    const float* __restrict__ xdbl, const float* __restrict__ A_log,
    float* __restrict__ Pbuf, float* __restrict__ Hbuf)
{
  int idx = blockIdx.x * 256 + threadIdx.x;    // NCHAN*NCH threads
  int chan = idx & (NCHAN - 1);
  int chunk = idx >> 12;
  int e = chan & (DI - 1);
  int b = chan >> 10;
  float Ae[NS];
#pragma unroll
  for (int n = 0; n < NS; ++n) Ae[n] = -expf(A_log[e * NS + n]);
  float h[NS], P[NS];
#pragma unroll
  for (int n = 0; n < NS; ++n) { h[n] = 0.f; P[n] = 1.f; }
  int m0 = b * L_ + chunk * TCH;
  for (int t = 0; t < TCH; ++t) {
    size_t m = (size_t)(m0 + t);
    float a = dtv[m * DI + e];
    float du = a * uc[m * DI + e];
    const float* bp = xdbl + m * XD + RK;
    float bv[NS];
#pragma unroll
    for (int n = 0; n < NS; n += 4) {
      float4 v = *(const float4*)(bp + n);
      bv[n] = v.x; bv[n + 1] = v.y; bv[n + 2] = v.z; bv[n + 3] = v.w;
    }
#pragma unroll
    for (int n = 0; n < NS; ++n) {
      float dA = expf(a * Ae[n]);
      P[n] *= dA;
      h[n] = dA * h[n] + du * bv[n];
    }
  }
  size_t base = (size_t)chunk * NS * NCHAN + chan;
#pragma unroll
  for (int n = 0; n < NS; ++n) {
    Pbuf[base + (size_t)n * NCHAN] = P[n];
    Hbuf[base + (size_t)n * NCHAN] = h[n];
  }
}

// ---------------- scan pass 2: compose chunk boundary states -----------------
__global__ __launch_bounds__(256) void scan_pass2(
    const float* __restrict__ Pbuf, const float* __restrict__ Hbuf,
    float* __restrict__ Hstart)
{
  int chan = blockIdx.x * 256 + threadIdx.x;   // NCHAN threads
  float hp[NS];
#pragma unroll
  for (int n = 0; n < NS; ++n) hp[n] = 0.f;
  for (int c = 0; c < NCH; ++c) {
    size_t base = (size_t)c * NS * NCHAN + chan;
#pragma unroll
    for (int n = 0; n < NS; ++n) {
      size_t o = base + (size_t)n * NCHAN;
      Hstart[o] = hp[n];
      hp[n] = Hbuf[o] + Pbuf[o] * hp[n];
    }
  }
}

// ---------------- scan pass 3: replay + y + gate + time-sum ------------------
__global__ __launch_bounds__(256) void scan_pass3(
    const float* __restrict__ dtv, const float* __restrict__ uc,
    const float* __restrict__ xdbl, const float* __restrict__ A_log,
    const float* __restrict__ Hstart, const float* __restrict__ z,
    const float* __restrict__ Dsk, float* __restrict__ sacc)
{
  int idx = blockIdx.x * 256 + threadIdx.x;    // NCHAN*NCH threads
  int chan = idx & (NCHAN - 1);
  int chunk = idx >> 12;
  int e = chan & (DI - 1);
  int b = chan >> 10;
  float Ae[NS];
#pragma unroll
  for (int n = 0; n < NS; ++n) Ae[n] = -expf(A_log[e * NS + n]);
  float h[NS];
  {
    size_t base = (size_t)chunk * NS * NCHAN + chan;
#pragma unroll
    for (int n = 0; n < NS; ++n) h[n] = Hstart[base + (size_t)n * NCHAN];
  }
  float Dv = Dsk[e];
  float ssum = 0.f;
  int m0 = b * L_ + chunk * TCH;
  for (int t = 0; t < TCH; ++t) {
    size_t m = (size_t)(m0 + t);
    float a = dtv[m * DI + e];
    float uu = uc[m * DI + e];
    float du = a * uu;
    const float* bp = xdbl + m * XD + RK;
    float bv[NS], cv[NS];
#pragma unroll
    for (int n = 0; n < NS; n += 4) {
      float4 v = *(const float4*)(bp + n);
      bv[n] = v.x; bv[n + 1] = v.y; bv[n + 2] = v.z; bv[n + 3] = v.w;
      float4 w = *(const float4*)(bp + NS + n);
      cv[n] = w.x; cv[n + 1] = w.y; cv[n + 2] = w.z; cv[n + 3] = w.w;
    }
    float y = 0.f;
#pragma unroll
    for (int n = 0; n < NS; ++n) {
      float dA = expf(a * Ae[n]);
      h[n] = dA * h[n] + du * bv[n];
      y += h[n] * cv[n];
    }
    float zz = z[m * DI + e];
    float gate = zz * (1.f / (1.f + expf(-zz)));  // silu(z)
    ssum += (y + uu * Dv) * gate;
  }
  atomicAdd(&sacc[chan], ssum);
}

// ---------------- final: out[b,d] = (s[b,:]/L) @ out_w -----------------------
__global__ __launch_bounds__(512) void out_proj_k(
    const float* __restrict__ s, const float* __restrict__ ow,
    float* __restrict__ out)
{
  int b = blockIdx.x;
  int d = threadIdx.x;              // 0..511
  const float* sb = s + b * DI;
  float acc = 0.f;
  for (int e = 0; e < DI; ++e) acc += sb[e] * ow[(size_t)e * DM + d];
  out[b * DM + d] = acc * (1.f / (float)L_);
}

extern "C" void kernel_launch(void* const* d_in, const int* in_sizes, int n_in,
                              void* d_out, int out_size, void* d_ws, size_t ws_size,
                              hipStream_t stream)
{
  const float* x      = (const float*)d_in[0];
  const float* w_proj = (const float*)d_in[1];
  const float* b_proj = (const float*)d_in[2];
  const float* in_w   = (const float*)d_in[3];
  const float* conv_w = (const float*)d_in[4];
  const float* conv_b = (const float*)d_in[5];
  const float* xproj_w= (const float*)d_in[6];
  const float* dt_w   = (const float*)d_in[7];
  const float* dt_b   = (const float*)d_in[8];
  const float* A_log  = (const float*)d_in[9];
  const float* D_skip = (const float*)d_in[10];
  const float* out_w  = (const float*)d_in[11];

  // Workspace (~236 MB): aliasing -> bufA: u then dtv; bufC: h then uc.
  float* ws   = (float*)d_ws;
  float* bufA = ws;
  float* bufZ = bufA + (size_t)M_ * DI;
  float* bufC = bufZ + (size_t)M_ * DI;
  float* xdbl = bufC + (size_t)M_ * DI;              // M*64
  float* Pb   = xdbl + (size_t)M_ * XD;
  float* Hb   = Pb   + (size_t)NCH * NS * NCHAN;
  float* Hs   = Hb   + (size_t)NCH * NS * NCHAN;
  float* sacc = Hs   + (size_t)NCH * NS * NCHAN;     // 4096 f
  unsigned short* wpT_hi = (unsigned short*)(sacc + NCHAN);
  unsigned short* wpT_lo = wpT_hi + (size_t)DIN * DM;        // 512x256
  unsigned short* inT_hi = wpT_lo + (size_t)DIN * DM;        // 2048x512
  unsigned short* inT_lo = inT_hi + (size_t)DM * 2 * DI;
  unsigned short* xpT_hi = inT_lo + (size_t)DM * 2 * DI;     // 64x1024
  unsigned short* xpT_lo = xpT_hi + (size_t)DI * XD;

  float* h   = bufC;
  float* u   = bufA;
  float* z   = bufZ;
  float* uc  = bufC;
  float* dtv = bufA;

  // 0. weight prep (transpose + hi/lo split)
  transpose_split<<<(DIN * DM + 255) / 256, 256, 0, stream>>>(w_proj, DIN, DM, wpT_hi, wpT_lo);
  transpose_split<<<(DM * 2 * DI + 255) / 256, 256, 0, stream>>>(in_w, DM, 2 * DI, inT_hi, inT_lo);
  transpose_split<<<(DI * XD + 255) / 256, 256, 0, stream>>>(xproj_w, DI, XD, xpT_hi, xpT_lo);

  // 1. h = x @ w_proj + b_proj                      [M, DM]
  gemm_split<128, 128, 64, 64><<<dim3(DM / 128, M_ / 128), 256, 0, stream>>>(
      x, wpT_hi, wpT_lo, b_proj, h, M_, DM, DIN, DM);
  // 2. u = h @ in_w[:, :DI] ; z = h @ in_w[:, DI:]  [M, DI] each
  gemm_split<128, 128, 64, 64><<<dim3(DI / 128, M_ / 128), 256, 0, stream>>>(
      h, inT_hi, inT_lo, nullptr, u, M_, DI, DM, DI);
  gemm_split<128, 128, 64, 64><<<dim3(DI / 128, M_ / 128), 256, 0, stream>>>(
      h, inT_hi + (size_t)DI * DM, inT_lo + (size_t)DI * DM, nullptr, z, M_, DI, DM, DI);
  // 3. uc = silu(causal_dwconv(u) + conv_b)         (overwrites h; h dead)
  conv_silu<<<(M_ * DI) / 256, 256, 0, stream>>>(u, conv_w, conv_b, uc);
  // 4. xdbl = uc @ xproj_w   (dt_raw | B | C)       [M, 64]
  gemm_split<64, 64, 32, 32><<<dim3(1, M_ / 64), 256, 0, stream>>>(
      uc, xpT_hi, xpT_lo, nullptr, xdbl, M_, XD, DI, XD);
  // 5. dtv = softplus(dt_raw @ dt_w + dt_b)         (overwrites u; u dead)
  dtproj_k<<<(M_ * DI) / 256, 256, 0, stream>>>(xdbl, dt_w, dt_b, dtv);
  // 6-8. chunked selective scan + gate + time-reduction
  scan_pass1<<<(NCHAN * NCH) / 256, 256, 0, stream>>>(dtv, uc, xdbl, A_log, Pb, Hb);
  scan_pass2<<<NCHAN / 256, 256, 0, stream>>>(Pb, Hb, Hs);
  hipMemsetAsync(sacc, 0, NCHAN * sizeof(float), stream);
  scan_pass3<<<(NCHAN * NCH) / 256, 256, 0, stream>>>(dtv, uc, xdbl, A_log, Hs, z, D_skip, sacc);
  // 9. out = (s/L) @ out_w
  out_proj_k<<<B_, DM, 0, stream>>>(sacc, out_w, (float*)d_out);
}

// Round 4
// 864.556 us; speedup vs baseline: 1.8218x; 1.3164x over previous
//
#include <hip/hip_runtime.h>
#include <cstdint>
#include <cstddef>

// Mamba backbone fwd: B=4, L=4096, IN=256, DM=512, DI=1024, N=16, R=32.
// Round 4: single-scan chunked selective scan (no replay) via
//   ssum_chunk = S_loc + G . h_start,  G[n] = sum_t gate_t C_t[n] cp_t[n];
// 4 threads per (chan,chunk) (4 states each) -> 2048 blocks, 8/CU.
// Fast transcendentals (v_exp_f32 / v_rcp_f32 / v_log_f32) everywhere.
// Split-bf16 MFMA GEMMs; u/z in_proj merged into one launch.

#define B_    4
#define L_    4096
#define M_    (B_ * L_)        // 16384 rows
#define DIN   256
#define DM    512
#define DI    1024
#define NS    16
#define RK    32
#define XD    64               // RK + 2*NS
#define TCH   128              // scan chunk length
#define NCH   (L_ / TCH)       // 32 chunks
#define NCHAN (B_ * DI)        // 4096 scalar channels

#define L2E   1.44269504088896f
#define LN2   0.69314718055995f

typedef __bf16 bf16_t;
typedef bf16_t bf16x8 __attribute__((ext_vector_type(8)));
typedef float  f32x4  __attribute__((ext_vector_type(4)));

static __device__ __forceinline__ float fexp2(float x)  { return __builtin_amdgcn_exp2f(x); }
static __device__ __forceinline__ float frcp(float x)   { return __builtin_amdgcn_rcpf(x); }
static __device__ __forceinline__ float flog2(float x)  { return __builtin_amdgcn_logf(x); }
static __device__ __forceinline__ float fsigmoid(float x) {
  return frcp(1.f + fexp2(-x * L2E));
}

static __device__ __forceinline__ unsigned short f32_to_bf16_rne(float f) {
  unsigned u = __float_as_uint(f);
  u += 0x7fffu + ((u >> 16) & 1u);
  return (unsigned short)(u >> 16);
}
static __device__ __forceinline__ float bf16_to_f32(unsigned short h) {
  return __uint_as_float(((unsigned)h) << 16);
}

// ---- weight prep: W[K][N] fp32 -> WT_hi[N][K], WT_lo[N][K] bf16 ------------
__global__ __launch_bounds__(256) void transpose_split(
    const float* __restrict__ W, int K, int N,
    unsigned short* __restrict__ Thi, unsigned short* __restrict__ Tlo)
{
  int idx = blockIdx.x * 256 + threadIdx.x;
  if (idx >= K * N) return;
  int k = idx % K, n = idx / K;          // writes coalesced along k
  float f = W[(size_t)k * N + n];
  unsigned short hi = f32_to_bf16_rne(f);
  float r = f - bf16_to_f32(hi);
  Thi[(size_t)n * K + k] = hi;
  Tlo[(size_t)n * K + k] = f32_to_bf16_rne(r);
}

// ---- split-bf16 MFMA GEMM: C[M,N] = A[M,K]fp32 x WT[N,K](hi/lo) (+bias) ----
// Columns >= splitN go to C2 (column gc-splitN). 3 mfma per fp32 product.
template<int BM, int BN, int WM, int WN>
__global__ __launch_bounds__(256) void gemm_split(
    const float* __restrict__ A, const unsigned short* __restrict__ Bhi,
    const unsigned short* __restrict__ Blo, const float* __restrict__ bias,
    float* __restrict__ C, float* __restrict__ C2,
    int M, int N, int K, int ldc, int splitN)
{
  constexpr int BK = 32, PAD = 40;
  constexpr int MT = WM / 16, NT = WN / 16;
  constexpr int WCOLS = BN / WN;
  __shared__ unsigned short lAhi[BM * PAD];
  __shared__ unsigned short lAlo[BM * PAD];
  __shared__ unsigned short lBhi[BN * PAD];
  __shared__ unsigned short lBlo[BN * PAD];

  const int tid  = threadIdx.x;
  const int wave = tid >> 6, lane = tid & 63;
  const int wm0 = (wave / WCOLS) * WM, wn0 = (wave % WCOLS) * WN;
  const int bm0 = blockIdx.y * BM, bn0 = blockIdx.x * BN;
  const int sr = tid >> 3;               // 0..31 staging row
  const int sc = (tid & 7) << 2;         // 0,4,...,28 staging k
  const int fm = lane & 15, fq = lane >> 4;

  f32x4 acc[MT][NT];
#pragma unroll
  for (int i = 0; i < MT; ++i)
#pragma unroll
    for (int j = 0; j < NT; ++j) acc[i][j] = 0.f;

  for (int k0 = 0; k0 < K; k0 += BK) {
#pragma unroll
    for (int r = sr; r < BM; r += 32) {
      float4 v = *(const float4*)(A + (size_t)(bm0 + r) * K + k0 + sc);
      unsigned short h0 = f32_to_bf16_rne(v.x), h1 = f32_to_bf16_rne(v.y);
      unsigned short h2 = f32_to_bf16_rne(v.z), h3 = f32_to_bf16_rne(v.w);
      ushort4 uh = make_ushort4(h0, h1, h2, h3);
      ushort4 ul = make_ushort4(f32_to_bf16_rne(v.x - bf16_to_f32(h0)),
                                f32_to_bf16_rne(v.y - bf16_to_f32(h1)),
                                f32_to_bf16_rne(v.z - bf16_to_f32(h2)),
                                f32_to_bf16_rne(v.w - bf16_to_f32(h3)));
      *(ushort4*)&lAhi[r * PAD + sc] = uh;
      *(ushort4*)&lAlo[r * PAD + sc] = ul;
    }
#pragma unroll
    for (int r = sr; r < BN; r += 32) {
      *(ushort4*)&lBhi[r * PAD + sc] =
          *(const ushort4*)(Bhi + (size_t)(bn0 + r) * K + k0 + sc);
      *(ushort4*)&lBlo[r * PAD + sc] =
          *(const ushort4*)(Blo + (size_t)(bn0 + r) * K + k0 + sc);
    }
    __syncthreads();
    bf16x8 ah[MT], al[MT];
#pragma unroll
    for (int i = 0; i < MT; ++i) {
      int row = wm0 + i * 16 + fm;
      ah[i] = *(const bf16x8*)&lAhi[row * PAD + fq * 8];
      al[i] = *(const bf16x8*)&lAlo[row * PAD + fq * 8];
    }
#pragma unroll
    for (int j = 0; j < NT; ++j) {
      int col = wn0 + j * 16 + fm;
      bf16x8 bh = *(const bf16x8*)&lBhi[col * PAD + fq * 8];
      bf16x8 bl = *(const bf16x8*)&lBlo[col * PAD + fq * 8];
#pragma unroll
      for (int i = 0; i < MT; ++i) {
        acc[i][j] = __builtin_amdgcn_mfma_f32_16x16x32_bf16(ah[i], bh, acc[i][j], 0, 0, 0);
        acc[i][j] = __builtin_amdgcn_mfma_f32_16x16x32_bf16(ah[i], bl, acc[i][j], 0, 0, 0);
        acc[i][j] = __builtin_amdgcn_mfma_f32_16x16x32_bf16(al[i], bh, acc[i][j], 0, 0, 0);
      }
    }
    __syncthreads();
  }
  // epilogue: C/D layout col=lane&15, row=quad*4+reg
#pragma unroll
  for (int j = 0; j < NT; ++j) {
    int gc = bn0 + wn0 + j * 16 + fm;
    float bv = bias ? bias[gc] : 0.f;
    float* dst = (gc < splitN) ? (C + gc) : (C2 + gc - splitN);
#pragma unroll
    for (int i = 0; i < MT; ++i) {
      int gr = bm0 + wm0 + i * 16 + fq * 4;
#pragma unroll
      for (int r = 0; r < 4; ++r)
        dst[(size_t)(gr + r) * ldc] = acc[i][j][r] + bv;
    }
  }
}

// ---------------- depthwise causal conv1d (4 taps) + silu --------------------
__global__ __launch_bounds__(256) void conv_silu(
    const float* __restrict__ u, const float* __restrict__ cw,
    const float* __restrict__ cb, float* __restrict__ uc)
{
  int idx = blockIdx.x * 256 + threadIdx.x;   // M_*DI threads
  int e = idx & (DI - 1);
  int m = idx >> 10;
  int t = m & (L_ - 1);
  const float* w = cw + e * 4;
  float acc = cb[e];
#pragma unroll
  for (int k = 0; k < 4; ++k) {
    int tt = t - 3 + k;
    if (tt >= 0) acc += u[(size_t)(m - 3 + k) * DI + e] * w[k];
  }
  uc[idx] = acc * fsigmoid(acc);
}

// ---------------- dt_proj + softplus: dtv[M,DI] ------------------------------
__global__ __launch_bounds__(256) void dtproj_k(
    const float* __restrict__ xdbl, const float* __restrict__ dtw,
    const float* __restrict__ dtb, float* __restrict__ dtv)
{
  int idx = blockIdx.x * 256 + threadIdx.x;    // M_*DI threads
  int e = idx & (DI - 1);
  int m = idx >> 10;
  const float* xr = xdbl + (size_t)m * XD;
  float acc = dtb[e];
#pragma unroll
  for (int k = 0; k < RK; ++k) acc += xr[k] * dtw[k * DI + e];
  // softplus = max(x,0) + log1p(exp(-|x|)), fast log2/exp2 path
  float t = fexp2(-fabsf(acc) * L2E);
  dtv[idx] = fmaxf(acc, 0.f) + flog2(1.f + t) * LN2;
}

// ---------------- fused scan: local scan + S_loc + (P,H,G) per chunk ---------
// grid (NCHAN/64, NCH), block 256 = 64 chans x 4 state-groups.
__global__ __launch_bounds__(256) void scan_fused(
    const float* __restrict__ dtv, const float* __restrict__ uc,
    const float* __restrict__ xdbl, const float* __restrict__ A_log,
    const float* __restrict__ z, const float* __restrict__ Dsk,
    float* __restrict__ Pbuf, float* __restrict__ Hbuf,
    float* __restrict__ Gbuf, float* __restrict__ sacc)
{
  const int l = threadIdx.x & 63;       // chan within group
  const int s = threadIdx.x >> 6;       // state-group 0..3
  const int chan = blockIdx.x * 64 + l;
  const int e = chan & (DI - 1);
  const int b = chan >> 10;
  const int chunk = blockIdx.y;

  float Aef[4];
#pragma unroll
  for (int j = 0; j < 4; ++j)
    Aef[j] = -__expf(A_log[e * NS + s * 4 + j]) * L2E;   // Ae * log2(e)
  const float Dv = (s == 0) ? Dsk[e] : 0.f;

  size_t m0 = (size_t)b * L_ + (size_t)chunk * TCH;
  const float* pd = dtv + m0 * DI + e;
  const float* pu = uc  + m0 * DI + e;
  const float* pz = z   + m0 * DI + e;
  const float* px = xdbl + m0 * XD + RK + s * 4;

  float h[4] = {0.f, 0.f, 0.f, 0.f};
  float cp[4] = {1.f, 1.f, 1.f, 1.f};
  float g[4] = {0.f, 0.f, 0.f, 0.f};
  float ssum = 0.f, asum = 0.f;

  for (int t = 0; t < TCH; ++t) {
    float a  = *pd;
    float uu = *pu;
    float zz = *pz;
    float4 bv = *(const float4*)px;          // B slice
    float4 cv = *(const float4*)(px + NS);   // C slice
    float gate = zz * fsigmoid(zz);
    float du = a * uu;
    asum += a;
    float bb[4] = {bv.x, bv.y, bv.z, bv.w};
    float cc[4] = {cv.x, cv.y, cv.z, cv.w};
    float y = 0.f;
#pragma unroll
    for (int j = 0; j < 4; ++j) {
      float dA = fexp2(a * Aef[j]);
      h[j] = fmaf(dA, h[j], du * bb[j]);
      cp[j] *= dA;
      g[j] = fmaf(gate * cp[j], cc[j], g[j]);
      y = fmaf(h[j], cc[j], y);
    }
    ssum = fmaf(gate, fmaf(uu, Dv, y), ssum);
    pd += DI; pu += DI; pz += DI; px += XD;
  }

  size_t base = ((size_t)chunk * NS + s * 4) * NCHAN + chan;
#pragma unroll
  for (int j = 0; j < 4; ++j) {
    Pbuf[base + (size_t)j * NCHAN] = fexp2(Aef[j] * asum);
    Hbuf[base + (size_t)j * NCHAN] = h[j];
    Gbuf[base + (size_t)j * NCHAN] = g[j];
  }
  atomicAdd(&sacc[chan], ssum);
}

// ---------------- compose chunk boundaries + boundary corrections ------------
__global__ __launch_bounds__(256) void scan_compose(
    const float* __restrict__ Pbuf, const float* __restrict__ Hbuf,
    const float* __restrict__ Gbuf, float* __restrict__ sacc)
{
  int chan = blockIdx.x * 256 + threadIdx.x;   // NCHAN threads
  float h0[NS];
#pragma unroll
  for (int n = 0; n < NS; ++n) h0[n] = 0.f;
  float acc = 0.f;
  for (int c = 0; c < NCH; ++c) {
    size_t base = (size_t)c * NS * NCHAN + chan;
#pragma unroll
    for (int n = 0; n < NS; ++n) {
      size_t o = base + (size_t)n * NCHAN;
      acc = fmaf(Gbuf[o], h0[n], acc);
      h0[n] = fmaf(Pbuf[o], h0[n], Hbuf[o]);
    }
  }
  sacc[chan] += acc;      // after scan_fused's atomics (stream-ordered)
}

// ---------------- final: out[b,d] = (s[b,:]/L) @ out_w -----------------------
__global__ __launch_bounds__(512) void out_proj_k(
    const float* __restrict__ s, const float* __restrict__ ow,
    float* __restrict__ out)
{
  int b = blockIdx.x;
  int d = threadIdx.x;              // 0..511
  const float* sb = s + b * DI;
  float acc = 0.f;
  for (int e = 0; e < DI; ++e) acc += sb[e] * ow[(size_t)e * DM + d];
  out[b * DM + d] = acc * (1.f / (float)L_);
}

extern "C" void kernel_launch(void* const* d_in, const int* in_sizes, int n_in,
                              void* d_out, int out_size, void* d_ws, size_t ws_size,
                              hipStream_t stream)
{
  const float* x      = (const float*)d_in[0];
  const float* w_proj = (const float*)d_in[1];
  const float* b_proj = (const float*)d_in[2];
  const float* in_w   = (const float*)d_in[3];
  const float* conv_w = (const float*)d_in[4];
  const float* conv_b = (const float*)d_in[5];
  const float* xproj_w= (const float*)d_in[6];
  const float* dt_w   = (const float*)d_in[7];
  const float* dt_b   = (const float*)d_in[8];
  const float* A_log  = (const float*)d_in[9];
  const float* D_skip = (const float*)d_in[10];
  const float* out_w  = (const float*)d_in[11];

  // Workspace (~236 MB): bufA: u -> dtv; bufZ: z; bufC: h -> uc.
  float* ws   = (float*)d_ws;
  float* bufA = ws;
  float* bufZ = bufA + (size_t)M_ * DI;
  float* bufC = bufZ + (size_t)M_ * DI;
  float* xdbl = bufC + (size_t)M_ * DI;              // M*64
  float* Pb   = xdbl + (size_t)M_ * XD;
  float* Hb   = Pb   + (size_t)NCH * NS * NCHAN;
  float* Gb   = Hb   + (size_t)NCH * NS * NCHAN;
  float* sacc = Gb   + (size_t)NCH * NS * NCHAN;     // 4096 f
  unsigned short* wpT_hi = (unsigned short*)(sacc + NCHAN);
  unsigned short* wpT_lo = wpT_hi + (size_t)DIN * DM;
  unsigned short* inT_hi = wpT_lo + (size_t)DIN * DM;
  unsigned short* inT_lo = inT_hi + (size_t)DM * 2 * DI;
  unsigned short* xpT_hi = inT_lo + (size_t)DM * 2 * DI;
  unsigned short* xpT_lo = xpT_hi + (size_t)DI * XD;

  float* h   = bufC;
  float* u   = bufA;
  float* z   = bufZ;
  float* uc  = bufC;
  float* dtv = bufA;

  // 0. weight prep
  transpose_split<<<(DIN * DM + 255) / 256, 256, 0, stream>>>(w_proj, DIN, DM, wpT_hi, wpT_lo);
  transpose_split<<<(DM * 2 * DI + 255) / 256, 256, 0, stream>>>(in_w, DM, 2 * DI, inT_hi, inT_lo);
  transpose_split<<<(DI * XD + 255) / 256, 256, 0, stream>>>(xproj_w, DI, XD, xpT_hi, xpT_lo);

  // 1. h = x @ w_proj + b_proj                      [M, DM]
  gemm_split<128, 128, 64, 64><<<dim3(DM / 128, M_ / 128), 256, 0, stream>>>(
      x, wpT_hi, wpT_lo, b_proj, h, h, M_, DM, DIN, DM, DM);
  // 2. (u|z) = h @ in_w  in ONE launch              [M, 2048] -> u,z [M,DI]
  gemm_split<128, 128, 64, 64><<<dim3(2 * DI / 128, M_ / 128), 256, 0, stream>>>(
      h, inT_hi, inT_lo, nullptr, u, z, M_, 2 * DI, DM, DI, DI);
  // 3. uc = silu(causal_dwconv(u) + conv_b)         (overwrites h; h dead)
  conv_silu<<<(M_ * DI) / 256, 256, 0, stream>>>(u, conv_w, conv_b, uc);
  // 4. xdbl = uc @ xproj_w   (dt_raw | B | C)       [M, 64]
  gemm_split<64, 64, 32, 32><<<dim3(1, M_ / 64), 256, 0, stream>>>(
      uc, xpT_hi, xpT_lo, nullptr, xdbl, xdbl, M_, XD, DI, XD, XD);
  // 5. dtv = softplus(dt_raw @ dt_w + dt_b)         (overwrites u; u dead)
  dtproj_k<<<(M_ * DI) / 256, 256, 0, stream>>>(xdbl, dt_w, dt_b, dtv);
  // 6. fused single-pass chunked scan
  hipMemsetAsync(sacc, 0, NCHAN * sizeof(float), stream);
  scan_fused<<<dim3(NCHAN / 64, NCH), 256, 0, stream>>>(
      dtv, uc, xdbl, A_log, z, D_skip, Pb, Hb, Gb, sacc);
  // 7. compose boundaries + corrections
  scan_compose<<<NCHAN / 256, 256, 0, stream>>>(Pb, Hb, Gb, sacc);
  // 8. out = (s/L) @ out_w
  out_proj_k<<<B_, DM, 0, stream>>>(sacc, out_w, (float*)d_out);
}

// Round 5
// 797.627 us; speedup vs baseline: 1.9747x; 1.0839x over previous
//
#include <hip/hip_runtime.h>
#include <cstdint>
#include <cstddef>

// Mamba backbone fwd: B=4, L=4096, IN=256, DM=512, DI=1024, N=16, R=32.
// Round 5: in_proj GEMM rebuilt m97-style — pre-split bf16 A (written by
// input_proj epilogue) + pre-split B, staged via global_load_lds width=16
// into fragment-linear LDS (zero bank conflicts, zero staging VALU).
// xproj gets split-K=4 (+reduce) to fix 1-block/CU starvation.
// All GEMMs remain 3-MFMA split-bf16 (output has ~1000x cancellation;
// 2-MFMA z-path would blow the absmax budget).

#define B_    4
#define L_    4096
#define M_    (B_ * L_)        // 16384 rows
#define DIN   256
#define DM    512
#define DI    1024
#define NS    16
#define RK    32
#define XD    64               // RK + 2*NS
#define TCH   128              // scan chunk length
#define NCH   (L_ / TCH)       // 32 chunks
#define NCHAN (B_ * DI)        // 4096 scalar channels

#define L2E   1.44269504088896f
#define LN2   0.69314718055995f

typedef __bf16 bf16_t;
typedef bf16_t bf16x8 __attribute__((ext_vector_type(8)));
typedef float  f32x4  __attribute__((ext_vector_type(4)));

static __device__ __forceinline__ float fexp2(float x)  { return __builtin_amdgcn_exp2f(x); }
static __device__ __forceinline__ float frcp(float x)   { return __builtin_amdgcn_rcpf(x); }
static __device__ __forceinline__ float flog2(float x)  { return __builtin_amdgcn_logf(x); }
static __device__ __forceinline__ float fsigmoid(float x) {
  return frcp(1.f + fexp2(-x * L2E));
}

static __device__ __forceinline__ unsigned short f32_to_bf16_rne(float f) {
  unsigned u = __float_as_uint(f);
  u += 0x7fffu + ((u >> 16) & 1u);
  return (unsigned short)(u >> 16);
}
static __device__ __forceinline__ float bf16_to_f32(unsigned short h) {
  return __uint_as_float(((unsigned)h) << 16);
}

// async global->LDS, 16 B per lane; LDS dst = wave-uniform base + lane*16.
typedef __attribute__((address_space(1))) const unsigned int ga_u32;
typedef __attribute__((address_space(3))) unsigned int ls_u32;
static __device__ __forceinline__ void glds16(const void* g, void* l) {
  __builtin_amdgcn_global_load_lds((ga_u32*)g, (ls_u32*)l, 16, 0, 0);
}

// ---- weight prep: W[K][N] fp32 -> WT_hi[N][K], WT_lo[N][K] bf16 ------------
__global__ __launch_bounds__(256) void transpose_split(
    const float* __restrict__ W, int K, int N,
    unsigned short* __restrict__ Thi, unsigned short* __restrict__ Tlo)
{
  int idx = blockIdx.x * 256 + threadIdx.x;
  if (idx >= K * N) return;
  int k = idx % K, n = idx / K;
  float f = W[(size_t)k * N + n];
  unsigned short hi = f32_to_bf16_rne(f);
  Thi[(size_t)n * K + k] = hi;
  Tlo[(size_t)n * K + k] = f32_to_bf16_rne(f - bf16_to_f32(hi));
}

// ---- input_proj: A fp32 on-the-fly split, OUTPUT = (hi,lo) bf16 pair -------
// 128x128 tile, 4 waves of 64x64, BK=32. (Round-4 staging; small kernel.)
__global__ __launch_bounds__(256) void gemm_in(
    const float* __restrict__ A, const unsigned short* __restrict__ Bhi,
    const unsigned short* __restrict__ Blo, const float* __restrict__ bias,
    unsigned short* __restrict__ Chi, unsigned short* __restrict__ Clo,
    int M, int N, int K, int ldc)
{
  constexpr int BM = 128, BN = 128, PAD = 40;
  __shared__ unsigned short lAhi[BM * PAD];
  __shared__ unsigned short lAlo[BM * PAD];
  __shared__ unsigned short lBhi[BN * PAD];
  __shared__ unsigned short lBlo[BN * PAD];
  const int tid  = threadIdx.x;
  const int wave = tid >> 6, lane = tid & 63;
  const int wm0 = (wave >> 1) * 64, wn0 = (wave & 1) * 64;
  const int bm0 = blockIdx.y * BM, bn0 = blockIdx.x * BN;
  const int sr = tid >> 3, sc = (tid & 7) << 2;
  const int fm = lane & 15, fq = lane >> 4;

  f32x4 acc[4][4];
#pragma unroll
  for (int i = 0; i < 4; ++i)
#pragma unroll
    for (int j = 0; j < 4; ++j) acc[i][j] = 0.f;

  for (int k0 = 0; k0 < K; k0 += 32) {
#pragma unroll
    for (int r = sr; r < BM; r += 32) {
      float4 v = *(const float4*)(A + (size_t)(bm0 + r) * K + k0 + sc);
      unsigned short h0 = f32_to_bf16_rne(v.x), h1 = f32_to_bf16_rne(v.y);
      unsigned short h2 = f32_to_bf16_rne(v.z), h3 = f32_to_bf16_rne(v.w);
      *(ushort4*)&lAhi[r * PAD + sc] = make_ushort4(h0, h1, h2, h3);
      *(ushort4*)&lAlo[r * PAD + sc] =
          make_ushort4(f32_to_bf16_rne(v.x - bf16_to_f32(h0)),
                       f32_to_bf16_rne(v.y - bf16_to_f32(h1)),
                       f32_to_bf16_rne(v.z - bf16_to_f32(h2)),
                       f32_to_bf16_rne(v.w - bf16_to_f32(h3)));
    }
#pragma unroll
    for (int r = sr; r < BN; r += 32) {
      *(ushort4*)&lBhi[r * PAD + sc] =
          *(const ushort4*)(Bhi + (size_t)(bn0 + r) * K + k0 + sc);
      *(ushort4*)&lBlo[r * PAD + sc] =
          *(const ushort4*)(Blo + (size_t)(bn0 + r) * K + k0 + sc);
    }
    __syncthreads();
    bf16x8 ah[4], al[4];
#pragma unroll
    for (int i = 0; i < 4; ++i) {
      int row = wm0 + i * 16 + fm;
      ah[i] = *(const bf16x8*)&lAhi[row * PAD + fq * 8];
      al[i] = *(const bf16x8*)&lAlo[row * PAD + fq * 8];
    }
#pragma unroll
    for (int j = 0; j < 4; ++j) {
      int col = wn0 + j * 16 + fm;
      bf16x8 bh = *(const bf16x8*)&lBhi[col * PAD + fq * 8];
      bf16x8 bl = *(const bf16x8*)&lBlo[col * PAD + fq * 8];
#pragma unroll
      for (int i = 0; i < 4; ++i) {
        acc[i][j] = __builtin_amdgcn_mfma_f32_16x16x32_bf16(ah[i], bh, acc[i][j], 0, 0, 0);
        acc[i][j] = __builtin_amdgcn_mfma_f32_16x16x32_bf16(ah[i], bl, acc[i][j], 0, 0, 0);
        acc[i][j] = __builtin_amdgcn_mfma_f32_16x16x32_bf16(al[i], bh, acc[i][j], 0, 0, 0);
      }
    }
    __syncthreads();
  }
#pragma unroll
  for (int j = 0; j < 4; ++j) {
    int gc = bn0 + wn0 + j * 16 + fm;
    float bv = bias ? bias[gc] : 0.f;
#pragma unroll
    for (int i = 0; i < 4; ++i) {
      int gr = bm0 + wm0 + i * 16 + fq * 4;
#pragma unroll
      for (int r = 0; r < 4; ++r) {
        float v = acc[i][j][r] + bv;
        unsigned short hi = f32_to_bf16_rne(v);
        Chi[(size_t)(gr + r) * ldc + gc] = hi;
        Clo[(size_t)(gr + r) * ldc + gc] = f32_to_bf16_rne(v - bf16_to_f32(hi));
      }
    }
  }
}

// ---- in_proj: pre-split A & B, global_load_lds, fragment-linear LDS --------
// 128x128 tile, BK=32, 4 waves (2x2 of 64x64). Subtile = 16r x 32k = 1024 B.
__global__ __launch_bounds__(256) void gemm_presplit3(
    const unsigned short* __restrict__ Ahi, const unsigned short* __restrict__ Alo,
    const unsigned short* __restrict__ Bhi, const unsigned short* __restrict__ Blo,
    float* __restrict__ C, float* __restrict__ C2,
    int M, int N, int K, int ldc, int splitN)
{
  __shared__ __align__(16) unsigned short lA[2][8 * 512];  // [hi/lo][subtile*512+lane*8]
  __shared__ __align__(16) unsigned short lB[2][8 * 512];
  const int tid = threadIdx.x, wave = tid >> 6, lane = tid & 63;
  const int r = lane & 15, kq = lane >> 4;        // frag row / k-quad
  const int bm0 = blockIdx.y * 128, bn0 = blockIdx.x * 128;
  const int wm = (wave >> 1) * 4, wn = (wave & 1) * 4;   // subtile bases
  const int s0 = wave * 2;                        // staging subtiles s0, s0+1

  const unsigned short* gAh = Ahi + (size_t)(bm0 + s0 * 16 + r) * K + kq * 8;
  const unsigned short* gAl = Alo + (size_t)(bm0 + s0 * 16 + r) * K + kq * 8;
  const unsigned short* gBh = Bhi + (size_t)(bn0 + s0 * 16 + r) * K + kq * 8;
  const unsigned short* gBl = Blo + (size_t)(bn0 + s0 * 16 + r) * K + kq * 8;
  const size_t rowK16 = (size_t)16 * K;

  f32x4 acc[4][4];
#pragma unroll
  for (int i = 0; i < 4; ++i)
#pragma unroll
    for (int j = 0; j < 4; ++j) acc[i][j] = 0.f;

  for (int k0 = 0; k0 < K; k0 += 32) {
    glds16(gAh,          &lA[0][s0 * 512]);
    glds16(gAh + rowK16, &lA[0][(s0 + 1) * 512]);
    glds16(gAl,          &lA[1][s0 * 512]);
    glds16(gAl + rowK16, &lA[1][(s0 + 1) * 512]);
    glds16(gBh,          &lB[0][s0 * 512]);
    glds16(gBh + rowK16, &lB[0][(s0 + 1) * 512]);
    glds16(gBl,          &lB[1][s0 * 512]);
    glds16(gBl + rowK16, &lB[1][(s0 + 1) * 512]);
    gAh += 32; gAl += 32; gBh += 32; gBl += 32;
    __syncthreads();                      // drains vmcnt before barrier
    bf16x8 ah[4], al[4];
#pragma unroll
    for (int i = 0; i < 4; ++i) {
      ah[i] = *(const bf16x8*)&lA[0][(wm + i) * 512 + lane * 8];
      al[i] = *(const bf16x8*)&lA[1][(wm + i) * 512 + lane * 8];
    }
#pragma unroll
    for (int j = 0; j < 4; ++j) {
      bf16x8 bh = *(const bf16x8*)&lB[0][(wn + j) * 512 + lane * 8];
      bf16x8 bl = *(const bf16x8*)&lB[1][(wn + j) * 512 + lane * 8];
#pragma unroll
      for (int i = 0; i < 4; ++i) {
        acc[i][j] = __builtin_amdgcn_mfma_f32_16x16x32_bf16(ah[i], bh, acc[i][j], 0, 0, 0);
        acc[i][j] = __builtin_amdgcn_mfma_f32_16x16x32_bf16(ah[i], bl, acc[i][j], 0, 0, 0);
        acc[i][j] = __builtin_amdgcn_mfma_f32_16x16x32_bf16(al[i], bh, acc[i][j], 0, 0, 0);
      }
    }
    __syncthreads();
  }
  // epilogue: C/D col=lane&15 (=r), row=kq*4+reg
#pragma unroll
  for (int j = 0; j < 4; ++j) {
    int gc = bn0 + (wn + j) * 16 + r;
    float* dst = (gc < splitN) ? (C + gc) : (C2 + gc - splitN);
#pragma unroll
    for (int i = 0; i < 4; ++i) {
      int gr = bm0 + (wm + i) * 16 + kq * 4;
#pragma unroll
      for (int rr = 0; rr < 4; ++rr)
        dst[(size_t)(gr + rr) * ldc] = acc[i][j][rr];
    }
  }
}

// ---- xproj split-K: A fp32 on-the-fly, 64x64 tile, K-slice per blockIdx.z --
__global__ __launch_bounds__(256) void gemm_splitk(
    const float* __restrict__ A, const unsigned short* __restrict__ Bhi,
    const unsigned short* __restrict__ Blo, float* __restrict__ Cpart,
    int M, int N, int K, int kslice)
{
  constexpr int BM = 64, BN = 64, PAD = 40;
  __shared__ unsigned short lAhi[BM * PAD];
  __shared__ unsigned short lAlo[BM * PAD];
  __shared__ unsigned short lBhi[BN * PAD];
  __shared__ unsigned short lBlo[BN * PAD];
  const int tid  = threadIdx.x;
  const int wave = tid >> 6, lane = tid & 63;
  const int wm0 = (wave >> 1) * 32, wn0 = (wave & 1) * 32;
  const int bm0 = blockIdx.y * BM, bn0 = blockIdx.x * BN;
  const int kz  = blockIdx.z;
  const int sr = tid >> 3, sc = (tid & 7) << 2;
  const int fm = lane & 15, fq = lane >> 4;
  float* Ck = Cpart + (size_t)kz * M * N;

  f32x4 acc[2][2];
#pragma unroll
  for (int i = 0; i < 2; ++i)
#pragma unroll
    for (int j = 0; j < 2; ++j) acc[i][j] = 0.f;

  const int kbeg = kz * kslice, kend = kbeg + kslice;
  for (int k0 = kbeg; k0 < kend; k0 += 32) {
#pragma unroll
    for (int r = sr; r < BM; r += 32) {
      float4 v = *(const float4*)(A + (size_t)(bm0 + r) * K + k0 + sc);
      unsigned short h0 = f32_to_bf16_rne(v.x), h1 = f32_to_bf16_rne(v.y);
      unsigned short h2 = f32_to_bf16_rne(v.z), h3 = f32_to_bf16_rne(v.w);
      *(ushort4*)&lAhi[r * PAD + sc] = make_ushort4(h0, h1, h2, h3);
      *(ushort4*)&lAlo[r * PAD + sc] =
          make_ushort4(f32_to_bf16_rne(v.x - bf16_to_f32(h0)),
                       f32_to_bf16_rne(v.y - bf16_to_f32(h1)),
                       f32_to_bf16_rne(v.z - bf16_to_f32(h2)),
                       f32_to_bf16_rne(v.w - bf16_to_f32(h3)));
    }
#pragma unroll
    for (int r = sr; r < BN; r += 32) {
      *(ushort4*)&lBhi[r * PAD + sc] =
          *(const ushort4*)(Bhi + (size_t)(bn0 + r) * K + k0 + sc);
      *(ushort4*)&lBlo[r * PAD + sc] =
          *(const ushort4*)(Blo + (size_t)(bn0 + r) * K + k0 + sc);
    }
    __syncthreads();
    bf16x8 ah[2], al[2];
#pragma unroll
    for (int i = 0; i < 2; ++i) {
      int row = wm0 + i * 16 + fm;
      ah[i] = *(const bf16x8*)&lAhi[row * PAD + fq * 8];
      al[i] = *(const bf16x8*)&lAlo[row * PAD + fq * 8];
    }
#pragma unroll
    for (int j = 0; j < 2; ++j) {
      int col = wn0 + j * 16 + fm;
      bf16x8 bh = *(const bf16x8*)&lBhi[col * PAD + fq * 8];
      bf16x8 bl = *(const bf16x8*)&lBlo[col * PAD + fq * 8];
#pragma unroll
      for (int i = 0; i < 2; ++i) {
        acc[i][j] = __builtin_amdgcn_mfma_f32_16x16x32_bf16(ah[i], bh, acc[i][j], 0, 0, 0);
        acc[i][j] = __builtin_amdgcn_mfma_f32_16x16x32_bf16(ah[i], bl, acc[i][j], 0, 0, 0);
        acc[i][j] = __builtin_amdgcn_mfma_f32_16x16x32_bf16(al[i], bh, acc[i][j], 0, 0, 0);
      }
    }
    __syncthreads();
  }
#pragma unroll
  for (int j = 0; j < 2; ++j) {
    int gc = bn0 + wn0 + j * 16 + fm;
#pragma unroll
    for (int i = 0; i < 2; ++i) {
      int gr = bm0 + wm0 + i * 16 + fq * 4;
#pragma unroll
      for (int rr = 0; rr < 4; ++rr)
        Ck[(size_t)(gr + rr) * N + gc] = acc[i][j][rr];
    }
  }
}

// ---- reduce split-K partials: xdbl = sum_kz xpart[kz] -----------------------
__global__ __launch_bounds__(256) void xreduce(
    const float* __restrict__ part, float* __restrict__ out)
{
  int i = (blockIdx.x * 256 + threadIdx.x) * 4;   // over M_*XD
  const size_t S = (size_t)M_ * XD;
  float4 a = *(const float4*)(part + i);
  float4 b = *(const float4*)(part + S + i);
  float4 c = *(const float4*)(part + 2 * S + i);
  float4 d = *(const float4*)(part + 3 * S + i);
  float4 o;
  o.x = (a.x + b.x) + (c.x + d.x);
  o.y = (a.y + b.y) + (c.y + d.y);
  o.z = (a.z + b.z) + (c.z + d.z);
  o.w = (a.w + b.w) + (c.w + d.w);
  *(float4*)(out + i) = o;
}

// ---------------- depthwise causal conv1d (4 taps) + silu --------------------
__global__ __launch_bounds__(256) void conv_silu(
    const float* __restrict__ u, const float* __restrict__ cw,
    const float* __restrict__ cb, float* __restrict__ uc)
{
  int idx = blockIdx.x * 256 + threadIdx.x;   // M_*DI threads
  int e = idx & (DI - 1);
  int m = idx >> 10;
  int t = m & (L_ - 1);
  const float* w = cw + e * 4;
  float acc = cb[e];
#pragma unroll
  for (int k = 0; k < 4; ++k) {
    int tt = t - 3 + k;
    if (tt >= 0) acc += u[(size_t)(m - 3 + k) * DI + e] * w[k];
  }
  uc[idx] = acc * fsigmoid(acc);
}

// ---------------- dt_proj + softplus: dtv[M,DI] ------------------------------
__global__ __launch_bounds__(256) void dtproj_k(
    const float* __restrict__ xdbl, const float* __restrict__ dtw,
    const float* __restrict__ dtb, float* __restrict__ dtv)
{
  int idx = blockIdx.x * 256 + threadIdx.x;    // M_*DI threads
  int e = idx & (DI - 1);
  int m = idx >> 10;
  const float* xr = xdbl + (size_t)m * XD;
  float acc = dtb[e];
#pragma unroll
  for (int k = 0; k < RK; ++k) acc += xr[k] * dtw[k * DI + e];
  float t = fexp2(-fabsf(acc) * L2E);
  dtv[idx] = fmaxf(acc, 0.f) + flog2(1.f + t) * LN2;   // softplus
}

// ---------------- fused scan: local scan + S_loc + (P,H,G) per chunk ---------
__global__ __launch_bounds__(256) void scan_fused(
    const float* __restrict__ dtv, const float* __restrict__ uc,
    const float* __restrict__ xdbl, const float* __restrict__ A_log,
    const float* __restrict__ z, const float* __restrict__ Dsk,
    float* __restrict__ Pbuf, float* __restrict__ Hbuf,
    float* __restrict__ Gbuf, float* __restrict__ sacc)
{
  const int l = threadIdx.x & 63;
  const int s = threadIdx.x >> 6;
  const int chan = blockIdx.x * 64 + l;
  const int e = chan & (DI - 1);
  const int b = chan >> 10;
  const int chunk = blockIdx.y;

  float Aef[4];
#pragma unroll
  for (int j = 0; j < 4; ++j)
    Aef[j] = -__expf(A_log[e * NS + s * 4 + j]) * L2E;
  const float Dv = (s == 0) ? Dsk[e] : 0.f;

  size_t m0 = (size_t)b * L_ + (size_t)chunk * TCH;
  const float* pd = dtv + m0 * DI + e;
  const float* pu = uc  + m0 * DI + e;
  const float* pz = z   + m0 * DI + e;
  const float* px = xdbl + m0 * XD + RK + s * 4;

  float h[4] = {0.f, 0.f, 0.f, 0.f};
  float cp[4] = {1.f, 1.f, 1.f, 1.f};
  float g[4] = {0.f, 0.f, 0.f, 0.f};
  float ssum = 0.f, asum = 0.f;

  for (int t = 0; t < TCH; ++t) {
    float a  = *pd;
    float uu = *pu;
    float zz = *pz;
    float4 bv = *(const float4*)px;
    float4 cv = *(const float4*)(px + NS);
    float gate = zz * fsigmoid(zz);
    float du = a * uu;
    asum += a;
    float bb[4] = {bv.x, bv.y, bv.z, bv.w};
    float cc[4] = {cv.x, cv.y, cv.z, cv.w};
    float y = 0.f;
#pragma unroll
    for (int j = 0; j < 4; ++j) {
      float dA = fexp2(a * Aef[j]);
      h[j] = fmaf(dA, h[j], du * bb[j]);
      cp[j] *= dA;
      g[j] = fmaf(gate * cp[j], cc[j], g[j]);
      y = fmaf(h[j], cc[j], y);
    }
    ssum = fmaf(gate, fmaf(uu, Dv, y), ssum);
    pd += DI; pu += DI; pz += DI; px += XD;
  }

  size_t base = ((size_t)chunk * NS + s * 4) * NCHAN + chan;
#pragma unroll
  for (int j = 0; j < 4; ++j) {
    Pbuf[base + (size_t)j * NCHAN] = fexp2(Aef[j] * asum);
    Hbuf[base + (size_t)j * NCHAN] = h[j];
    Gbuf[base + (size_t)j * NCHAN] = g[j];
  }
  atomicAdd(&sacc[chan], ssum);
}

// ---------------- compose chunk boundaries + boundary corrections ------------
__global__ __launch_bounds__(256) void scan_compose(
    const float* __restrict__ Pbuf, const float* __restrict__ Hbuf,
    const float* __restrict__ Gbuf, float* __restrict__ sacc)
{
  int chan = blockIdx.x * 256 + threadIdx.x;
  float h0[NS];
#pragma unroll
  for (int n = 0; n < NS; ++n) h0[n] = 0.f;
  float acc = 0.f;
  for (int c = 0; c < NCH; ++c) {
    size_t base = (size_t)c * NS * NCHAN + chan;
#pragma unroll
    for (int n = 0; n < NS; ++n) {
      size_t o = base + (size_t)n * NCHAN;
      acc = fmaf(Gbuf[o], h0[n], acc);
      h0[n] = fmaf(Pbuf[o], h0[n], Hbuf[o]);
    }
  }
  sacc[chan] += acc;
}

// ---------------- final: out[b,d] = (s[b,:]/L) @ out_w -----------------------
__global__ __launch_bounds__(512) void out_proj_k(
    const float* __restrict__ s, const float* __restrict__ ow,
    float* __restrict__ out)
{
  int b = blockIdx.x;
  int d = threadIdx.x;
  const float* sb = s + b * DI;
  float acc = 0.f;
  for (int e = 0; e < DI; ++e) acc += sb[e] * ow[(size_t)e * DM + d];
  out[b * DM + d] = acc * (1.f / (float)L_);
}

extern "C" void kernel_launch(void* const* d_in, const int* in_sizes, int n_in,
                              void* d_out, int out_size, void* d_ws, size_t ws_size,
                              hipStream_t stream)
{
  const float* x      = (const float*)d_in[0];
  const float* w_proj = (const float*)d_in[1];
  const float* b_proj = (const float*)d_in[2];
  const float* in_w   = (const float*)d_in[3];
  const float* conv_w = (const float*)d_in[4];
  const float* conv_b = (const float*)d_in[5];
  const float* xproj_w= (const float*)d_in[6];
  const float* dt_w   = (const float*)d_in[7];
  const float* dt_b   = (const float*)d_in[8];
  const float* A_log  = (const float*)d_in[9];
  const float* D_skip = (const float*)d_in[10];
  const float* out_w  = (const float*)d_in[11];

  // Workspace (~236 MB): bufA: u -> dtv; bufZ: z; bufC: h(hi/lo bf16) -> uc.
  float* ws   = (float*)d_ws;
  float* bufA = ws;
  float* bufZ = bufA + (size_t)M_ * DI;
  float* bufC = bufZ + (size_t)M_ * DI;
  float* xdbl = bufC + (size_t)M_ * DI;              // M*64
  float* Pb   = xdbl + (size_t)M_ * XD;
  float* Hb   = Pb   + (size_t)NCH * NS * NCHAN;
  float* Gb   = Hb   + (size_t)NCH * NS * NCHAN;
  float* sacc = Gb   + (size_t)NCH * NS * NCHAN;     // 4096 f
  unsigned short* wpT_hi = (unsigned short*)(sacc + NCHAN);
  unsigned short* wpT_lo = wpT_hi + (size_t)DIN * DM;
  unsigned short* inT_hi = wpT_lo + (size_t)DIN * DM;
  unsigned short* inT_lo = inT_hi + (size_t)DM * 2 * DI;
  unsigned short* xpT_hi = inT_lo + (size_t)DM * 2 * DI;
  unsigned short* xpT_lo = xpT_hi + (size_t)DI * XD;

  unsigned short* h_hi = (unsigned short*)bufC;      // h as split-bf16 pair
  unsigned short* h_lo = h_hi + (size_t)M_ * DM;     // (33.5 MB of bufC)
  float* u    = bufA;
  float* z    = bufZ;
  float* uc   = bufC;                                 // overwrites h (dead)
  float* dtv  = bufA;                                 // overwrites u (dead)
  float* xpart = Pb;                                  // 4*M*XD f, dead pre-scan

  // 0. weight prep
  transpose_split<<<(DIN * DM + 255) / 256, 256, 0, stream>>>(w_proj, DIN, DM, wpT_hi, wpT_lo);
  transpose_split<<<(DM * 2 * DI + 255) / 256, 256, 0, stream>>>(in_w, DM, 2 * DI, inT_hi, inT_lo);
  transpose_split<<<(DI * XD + 255) / 256, 256, 0, stream>>>(xproj_w, DI, XD, xpT_hi, xpT_lo);

  // 1. h = x @ w_proj + b_proj  -> split bf16 pair  [M, DM]
  gemm_in<<<dim3(DM / 128, M_ / 128), 256, 0, stream>>>(
      x, wpT_hi, wpT_lo, b_proj, h_hi, h_lo, M_, DM, DIN, DM);
  // 2. (u|z) = h @ in_w, one launch, m97-style      [M, 2048] -> u,z [M,DI]
  gemm_presplit3<<<dim3(2 * DI / 128, M_ / 128), 256, 0, stream>>>(
      h_hi, h_lo, inT_hi, inT_lo, u, z, M_, 2 * DI, DM, DI, DI);
  // 3. uc = silu(causal_dwconv(u) + conv_b)         (overwrites h; h dead)
  conv_silu<<<(M_ * DI) / 256, 256, 0, stream>>>(u, conv_w, conv_b, uc);
  // 4. xdbl = uc @ xproj_w, split-K=4               [M, 64]
  gemm_splitk<<<dim3(1, M_ / 64, 4), 256, 0, stream>>>(
      uc, xpT_hi, xpT_lo, xpart, M_, XD, DI, DI / 4);
  xreduce<<<(M_ * XD) / 1024, 256, 0, stream>>>(xpart, xdbl);
  // 5. dtv = softplus(dt_raw @ dt_w + dt_b)         (overwrites u; u dead)
  dtproj_k<<<(M_ * DI) / 256, 256, 0, stream>>>(xdbl, dt_w, dt_b, dtv);
  // 6. fused single-pass chunked scan
  hipMemsetAsync(sacc, 0, NCHAN * sizeof(float), stream);
  scan_fused<<<dim3(NCHAN / 64, NCH), 256, 0, stream>>>(
      dtv, uc, xdbl, A_log, z, D_skip, Pb, Hb, Gb, sacc);
  // 7. compose boundaries + corrections
  scan_compose<<<NCHAN / 256, 256, 0, stream>>>(Pb, Hb, Gb, sacc);
  // 8. out = (s/L) @ out_w
  out_proj_k<<<B_, DM, 0, stream>>>(sacc, out_w, (float*)d_out);
}

// Round 6
// 605.888 us; speedup vs baseline: 2.5996x; 1.3165x over previous
//
#include <hip/hip_runtime.h>
#include <cstdint>
#include <cstddef>

// Mamba backbone fwd: B=4, L=4096, IN=256, DM=512, DI=1024, N=16, R=32.
// Round 6: parallelize the latency-starved tail kernels.
//  - scan_compose: 1 thread per (chan,state) = 65536 threads (was 4096),
//    coalesced loads, additive gate-correction via atomicAdd.
//  - out_proj: split-E over 256 single-wave blocks + atomicAdd into zeroed out.
//  - transpose_split: LDS 32x33 tiled (both sides coalesced).
// GEMMs/scan unchanged from round 5.

#define B_    4
#define L_    4096
#define M_    (B_ * L_)        // 16384 rows
#define DIN   256
#define DM    512
#define DI    1024
#define NS    16
#define RK    32
#define XD    64               // RK + 2*NS
#define TCH   128              // scan chunk length
#define NCH   (L_ / TCH)       // 32 chunks
#define NCHAN (B_ * DI)        // 4096 scalar channels

#define L2E   1.44269504088896f
#define LN2   0.69314718055995f

typedef __bf16 bf16_t;
typedef bf16_t bf16x8 __attribute__((ext_vector_type(8)));
typedef float  f32x4  __attribute__((ext_vector_type(4)));

static __device__ __forceinline__ float fexp2(float x)  { return __builtin_amdgcn_exp2f(x); }
static __device__ __forceinline__ float frcp(float x)   { return __builtin_amdgcn_rcpf(x); }
static __device__ __forceinline__ float flog2(float x)  { return __builtin_amdgcn_logf(x); }
static __device__ __forceinline__ float fsigmoid(float x) {
  return frcp(1.f + fexp2(-x * L2E));
}

static __device__ __forceinline__ unsigned short f32_to_bf16_rne(float f) {
  unsigned u = __float_as_uint(f);
  u += 0x7fffu + ((u >> 16) & 1u);
  return (unsigned short)(u >> 16);
}
static __device__ __forceinline__ float bf16_to_f32(unsigned short h) {
  return __uint_as_float(((unsigned)h) << 16);
}

// async global->LDS, 16 B per lane; LDS dst = wave-uniform base + lane*16.
typedef __attribute__((address_space(1))) const unsigned int ga_u32;
typedef __attribute__((address_space(3))) unsigned int ls_u32;
static __device__ __forceinline__ void glds16(const void* g, void* l) {
  __builtin_amdgcn_global_load_lds((ga_u32*)g, (ls_u32*)l, 16, 0, 0);
}

// ---- weight prep: W[K][N] fp32 -> WT_hi[N][K], WT_lo[N][K] bf16 ------------
// LDS 32x33 tiled transpose: coalesced reads (along n) AND writes (along k).
__global__ __launch_bounds__(256) void transpose_split(
    const float* __restrict__ W, int K, int N,
    unsigned short* __restrict__ Thi, unsigned short* __restrict__ Tlo)
{
  __shared__ float tile[32][33];
  const int kt = blockIdx.x * 32, nt = blockIdx.y * 32;
  const int tx = threadIdx.x & 31, ty = threadIdx.x >> 5;   // ty 0..7
#pragma unroll
  for (int i = ty; i < 32; i += 8)
    tile[i][tx] = W[(size_t)(kt + i) * N + nt + tx];
  __syncthreads();
#pragma unroll
  for (int i = ty; i < 32; i += 8) {
    float f = tile[tx][i];                 // k = kt+tx, n = nt+i
    unsigned short hi = f32_to_bf16_rne(f);
    size_t o = (size_t)(nt + i) * K + kt + tx;
    Thi[o] = hi;
    Tlo[o] = f32_to_bf16_rne(f - bf16_to_f32(hi));
  }
}

// ---- input_proj: A fp32 on-the-fly split, OUTPUT = (hi,lo) bf16 pair -------
__global__ __launch_bounds__(256) void gemm_in(
    const float* __restrict__ A, const unsigned short* __restrict__ Bhi,
    const unsigned short* __restrict__ Blo, const float* __restrict__ bias,
    unsigned short* __restrict__ Chi, unsigned short* __restrict__ Clo,
    int M, int N, int K, int ldc)
{
  constexpr int BM = 128, BN = 128, PAD = 40;
  __shared__ unsigned short lAhi[BM * PAD];
  __shared__ unsigned short lAlo[BM * PAD];
  __shared__ unsigned short lBhi[BN * PAD];
  __shared__ unsigned short lBlo[BN * PAD];
  const int tid  = threadIdx.x;
  const int wave = tid >> 6, lane = tid & 63;
  const int wm0 = (wave >> 1) * 64, wn0 = (wave & 1) * 64;
  const int bm0 = blockIdx.y * BM, bn0 = blockIdx.x * BN;
  const int sr = tid >> 3, sc = (tid & 7) << 2;
  const int fm = lane & 15, fq = lane >> 4;

  f32x4 acc[4][4];
#pragma unroll
  for (int i = 0; i < 4; ++i)
#pragma unroll
    for (int j = 0; j < 4; ++j) acc[i][j] = 0.f;

  for (int k0 = 0; k0 < K; k0 += 32) {
#pragma unroll
    for (int r = sr; r < BM; r += 32) {
      float4 v = *(const float4*)(A + (size_t)(bm0 + r) * K + k0 + sc);
      unsigned short h0 = f32_to_bf16_rne(v.x), h1 = f32_to_bf16_rne(v.y);
      unsigned short h2 = f32_to_bf16_rne(v.z), h3 = f32_to_bf16_rne(v.w);
      *(ushort4*)&lAhi[r * PAD + sc] = make_ushort4(h0, h1, h2, h3);
      *(ushort4*)&lAlo[r * PAD + sc] =
          make_ushort4(f32_to_bf16_rne(v.x - bf16_to_f32(h0)),
                       f32_to_bf16_rne(v.y - bf16_to_f32(h1)),
                       f32_to_bf16_rne(v.z - bf16_to_f32(h2)),
                       f32_to_bf16_rne(v.w - bf16_to_f32(h3)));
    }
#pragma unroll
    for (int r = sr; r < BN; r += 32) {
      *(ushort4*)&lBhi[r * PAD + sc] =
          *(const ushort4*)(Bhi + (size_t)(bn0 + r) * K + k0 + sc);
      *(ushort4*)&lBlo[r * PAD + sc] =
          *(const ushort4*)(Blo + (size_t)(bn0 + r) * K + k0 + sc);
    }
    __syncthreads();
    bf16x8 ah[4], al[4];
#pragma unroll
    for (int i = 0; i < 4; ++i) {
      int row = wm0 + i * 16 + fm;
      ah[i] = *(const bf16x8*)&lAhi[row * PAD + fq * 8];
      al[i] = *(const bf16x8*)&lAlo[row * PAD + fq * 8];
    }
#pragma unroll
    for (int j = 0; j < 4; ++j) {
      int col = wn0 + j * 16 + fm;
      bf16x8 bh = *(const bf16x8*)&lBhi[col * PAD + fq * 8];
      bf16x8 bl = *(const bf16x8*)&lBlo[col * PAD + fq * 8];
#pragma unroll
      for (int i = 0; i < 4; ++i) {
        acc[i][j] = __builtin_amdgcn_mfma_f32_16x16x32_bf16(ah[i], bh, acc[i][j], 0, 0, 0);
        acc[i][j] = __builtin_amdgcn_mfma_f32_16x16x32_bf16(ah[i], bl, acc[i][j], 0, 0, 0);
        acc[i][j] = __builtin_amdgcn_mfma_f32_16x16x32_bf16(al[i], bh, acc[i][j], 0, 0, 0);
      }
    }
    __syncthreads();
  }
#pragma unroll
  for (int j = 0; j < 4; ++j) {
    int gc = bn0 + wn0 + j * 16 + fm;
    float bv = bias ? bias[gc] : 0.f;
#pragma unroll
    for (int i = 0; i < 4; ++i) {
      int gr = bm0 + wm0 + i * 16 + fq * 4;
#pragma unroll
      for (int r = 0; r < 4; ++r) {
        float v = acc[i][j][r] + bv;
        unsigned short hi = f32_to_bf16_rne(v);
        Chi[(size_t)(gr + r) * ldc + gc] = hi;
        Clo[(size_t)(gr + r) * ldc + gc] = f32_to_bf16_rne(v - bf16_to_f32(hi));
      }
    }
  }
}

// ---- in_proj: pre-split A & B, global_load_lds, fragment-linear LDS --------
__global__ __launch_bounds__(256) void gemm_presplit3(
    const unsigned short* __restrict__ Ahi, const unsigned short* __restrict__ Alo,
    const unsigned short* __restrict__ Bhi, const unsigned short* __restrict__ Blo,
    float* __restrict__ C, float* __restrict__ C2,
    int M, int N, int K, int ldc, int splitN)
{
  __shared__ __align__(16) unsigned short lA[2][8 * 512];
  __shared__ __align__(16) unsigned short lB[2][8 * 512];
  const int tid = threadIdx.x, wave = tid >> 6, lane = tid & 63;
  const int r = lane & 15, kq = lane >> 4;
  const int bm0 = blockIdx.y * 128, bn0 = blockIdx.x * 128;
  const int wm = (wave >> 1) * 4, wn = (wave & 1) * 4;
  const int s0 = wave * 2;

  const unsigned short* gAh = Ahi + (size_t)(bm0 + s0 * 16 + r) * K + kq * 8;
  const unsigned short* gAl = Alo + (size_t)(bm0 + s0 * 16 + r) * K + kq * 8;
  const unsigned short* gBh = Bhi + (size_t)(bn0 + s0 * 16 + r) * K + kq * 8;
  const unsigned short* gBl = Blo + (size_t)(bn0 + s0 * 16 + r) * K + kq * 8;
  const size_t rowK16 = (size_t)16 * K;

  f32x4 acc[4][4];
#pragma unroll
  for (int i = 0; i < 4; ++i)
#pragma unroll
    for (int j = 0; j < 4; ++j) acc[i][j] = 0.f;

  for (int k0 = 0; k0 < K; k0 += 32) {
    glds16(gAh,          &lA[0][s0 * 512]);
    glds16(gAh + rowK16, &lA[0][(s0 + 1) * 512]);
    glds16(gAl,          &lA[1][s0 * 512]);
    glds16(gAl + rowK16, &lA[1][(s0 + 1) * 512]);
    glds16(gBh,          &lB[0][s0 * 512]);
    glds16(gBh + rowK16, &lB[0][(s0 + 1) * 512]);
    glds16(gBl,          &lB[1][s0 * 512]);
    glds16(gBl + rowK16, &lB[1][(s0 + 1) * 512]);
    gAh += 32; gAl += 32; gBh += 32; gBl += 32;
    __syncthreads();
    bf16x8 ah[4], al[4];
#pragma unroll
    for (int i = 0; i < 4; ++i) {
      ah[i] = *(const bf16x8*)&lA[0][(wm + i) * 512 + lane * 8];
      al[i] = *(const bf16x8*)&lA[1][(wm + i) * 512 + lane * 8];
    }
#pragma unroll
    for (int j = 0; j < 4; ++j) {
      bf16x8 bh = *(const bf16x8*)&lB[0][(wn + j) * 512 + lane * 8];
      bf16x8 bl = *(const bf16x8*)&lB[1][(wn + j) * 512 + lane * 8];
#pragma unroll
      for (int i = 0; i < 4; ++i) {
        acc[i][j] = __builtin_amdgcn_mfma_f32_16x16x32_bf16(ah[i], bh, acc[i][j], 0, 0, 0);
        acc[i][j] = __builtin_amdgcn_mfma_f32_16x16x32_bf16(ah[i], bl, acc[i][j], 0, 0, 0);
        acc[i][j] = __builtin_amdgcn_mfma_f32_16x16x32_bf16(al[i], bh, acc[i][j], 0, 0, 0);
      }
    }
    __syncthreads();
  }
#pragma unroll
  for (int j = 0; j < 4; ++j) {
    int gc = bn0 + (wn + j) * 16 + r;
    float* dst = (gc < splitN) ? (C + gc) : (C2 + gc - splitN);
#pragma unroll
    for (int i = 0; i < 4; ++i) {
      int gr = bm0 + (wm + i) * 16 + kq * 4;
#pragma unroll
      for (int rr = 0; rr < 4; ++rr)
        dst[(size_t)(gr + rr) * ldc] = acc[i][j][rr];
    }
  }
}

// ---- xproj split-K: A fp32 on-the-fly, 64x64 tile, K-slice per blockIdx.z --
__global__ __launch_bounds__(256) void gemm_splitk(
    const float* __restrict__ A, const unsigned short* __restrict__ Bhi,
    const unsigned short* __restrict__ Blo, float* __restrict__ Cpart,
    int M, int N, int K, int kslice)
{
  constexpr int BM = 64, BN = 64, PAD = 40;
  __shared__ unsigned short lAhi[BM * PAD];
  __shared__ unsigned short lAlo[BM * PAD];
  __shared__ unsigned short lBhi[BN * PAD];
  __shared__ unsigned short lBlo[BN * PAD];
  const int tid  = threadIdx.x;
  const int wave = tid >> 6, lane = tid & 63;
  const int wm0 = (wave >> 1) * 32, wn0 = (wave & 1) * 32;
  const int bm0 = blockIdx.y * BM, bn0 = blockIdx.x * BN;
  const int kz  = blockIdx.z;
  const int sr = tid >> 3, sc = (tid & 7) << 2;
  const int fm = lane & 15, fq = lane >> 4;
  float* Ck = Cpart + (size_t)kz * M * N;

  f32x4 acc[2][2];
#pragma unroll
  for (int i = 0; i < 2; ++i)
#pragma unroll
    for (int j = 0; j < 2; ++j) acc[i][j] = 0.f;

  const int kbeg = kz * kslice, kend = kbeg + kslice;
  for (int k0 = kbeg; k0 < kend; k0 += 32) {
#pragma unroll
    for (int r = sr; r < BM; r += 32) {
      float4 v = *(const float4*)(A + (size_t)(bm0 + r) * K + k0 + sc);
      unsigned short h0 = f32_to_bf16_rne(v.x), h1 = f32_to_bf16_rne(v.y);
      unsigned short h2 = f32_to_bf16_rne(v.z), h3 = f32_to_bf16_rne(v.w);
      *(ushort4*)&lAhi[r * PAD + sc] = make_ushort4(h0, h1, h2, h3);
      *(ushort4*)&lAlo[r * PAD + sc] =
          make_ushort4(f32_to_bf16_rne(v.x - bf16_to_f32(h0)),
                       f32_to_bf16_rne(v.y - bf16_to_f32(h1)),
                       f32_to_bf16_rne(v.z - bf16_to_f32(h2)),
                       f32_to_bf16_rne(v.w - bf16_to_f32(h3)));
    }
#pragma unroll
    for (int r = sr; r < BN; r += 32) {
      *(ushort4*)&lBhi[r * PAD + sc] =
          *(const ushort4*)(Bhi + (size_t)(bn0 + r) * K + k0 + sc);
      *(ushort4*)&lBlo[r * PAD + sc] =
          *(const ushort4*)(Blo + (size_t)(bn0 + r) * K + k0 + sc);
    }
    __syncthreads();
    bf16x8 ah[2], al[2];
#pragma unroll
    for (int i = 0; i < 2; ++i) {
      int row = wm0 + i * 16 + fm;
      ah[i] = *(const bf16x8*)&lAhi[row * PAD + fq * 8];
      al[i] = *(const bf16x8*)&lAlo[row * PAD + fq * 8];
    }
#pragma unroll
    for (int j = 0; j < 2; ++j) {
      int col = wn0 + j * 16 + fm;
      bf16x8 bh = *(const bf16x8*)&lBhi[col * PAD + fq * 8];
      bf16x8 bl = *(const bf16x8*)&lBlo[col * PAD + fq * 8];
#pragma unroll
      for (int i = 0; i < 2; ++i) {
        acc[i][j] = __builtin_amdgcn_mfma_f32_16x16x32_bf16(ah[i], bh, acc[i][j], 0, 0, 0);
        acc[i][j] = __builtin_amdgcn_mfma_f32_16x16x32_bf16(ah[i], bl, acc[i][j], 0, 0, 0);
        acc[i][j] = __builtin_amdgcn_mfma_f32_16x16x32_bf16(al[i], bh, acc[i][j], 0, 0, 0);
      }
    }
    __syncthreads();
  }
#pragma unroll
  for (int j = 0; j < 2; ++j) {
    int gc = bn0 + wn0 + j * 16 + fm;
#pragma unroll
    for (int i = 0; i < 2; ++i) {
      int gr = bm0 + wm0 + i * 16 + fq * 4;
#pragma unroll
      for (int rr = 0; rr < 4; ++rr)
        Ck[(size_t)(gr + rr) * N + gc] = acc[i][j][rr];
    }
  }
}

// ---- reduce split-K partials: xdbl = sum_kz xpart[kz] -----------------------
__global__ __launch_bounds__(256) void xreduce(
    const float* __restrict__ part, float* __restrict__ out)
{
  int i = (blockIdx.x * 256 + threadIdx.x) * 4;
  const size_t S = (size_t)M_ * XD;
  float4 a = *(const float4*)(part + i);
  float4 b = *(const float4*)(part + S + i);
  float4 c = *(const float4*)(part + 2 * S + i);
  float4 d = *(const float4*)(part + 3 * S + i);
  float4 o;
  o.x = (a.x + b.x) + (c.x + d.x);
  o.y = (a.y + b.y) + (c.y + d.y);
  o.z = (a.z + b.z) + (c.z + d.z);
  o.w = (a.w + b.w) + (c.w + d.w);
  *(float4*)(out + i) = o;
}

// ---------------- depthwise causal conv1d (4 taps) + silu --------------------
__global__ __launch_bounds__(256) void conv_silu(
    const float* __restrict__ u, const float* __restrict__ cw,
    const float* __restrict__ cb, float* __restrict__ uc)
{
  int idx = blockIdx.x * 256 + threadIdx.x;
  int e = idx & (DI - 1);
  int m = idx >> 10;
  int t = m & (L_ - 1);
  const float* w = cw + e * 4;
  float acc = cb[e];
#pragma unroll
  for (int k = 0; k < 4; ++k) {
    int tt = t - 3 + k;
    if (tt >= 0) acc += u[(size_t)(m - 3 + k) * DI + e] * w[k];
  }
  uc[idx] = acc * fsigmoid(acc);
}

// ---------------- dt_proj + softplus: dtv[M,DI] ------------------------------
__global__ __launch_bounds__(256) void dtproj_k(
    const float* __restrict__ xdbl, const float* __restrict__ dtw,
    const float* __restrict__ dtb, float* __restrict__ dtv)
{
  int idx = blockIdx.x * 256 + threadIdx.x;
  int e = idx & (DI - 1);
  int m = idx >> 10;
  const float* xr = xdbl + (size_t)m * XD;
  float acc = dtb[e];
#pragma unroll
  for (int k = 0; k < RK; ++k) acc += xr[k] * dtw[k * DI + e];
  float t = fexp2(-fabsf(acc) * L2E);
  dtv[idx] = fmaxf(acc, 0.f) + flog2(1.f + t) * LN2;
}

// ---------------- fused scan: local scan + S_loc + (P,H,G) per chunk ---------
__global__ __launch_bounds__(256) void scan_fused(
    const float* __restrict__ dtv, const float* __restrict__ uc,
    const float* __restrict__ xdbl, const float* __restrict__ A_log,
    const float* __restrict__ z, const float* __restrict__ Dsk,
    float* __restrict__ Pbuf, float* __restrict__ Hbuf,
    float* __restrict__ Gbuf, float* __restrict__ sacc)
{
  const int l = threadIdx.x & 63;
  const int s = threadIdx.x >> 6;
  const int chan = blockIdx.x * 64 + l;
  const int e = chan & (DI - 1);
  const int b = chan >> 10;
  const int chunk = blockIdx.y;

  float Aef[4];
#pragma unroll
  for (int j = 0; j < 4; ++j)
    Aef[j] = -__expf(A_log[e * NS + s * 4 + j]) * L2E;
  const float Dv = (s == 0) ? Dsk[e] : 0.f;

  size_t m0 = (size_t)b * L_ + (size_t)chunk * TCH;
  const float* pd = dtv + m0 * DI + e;
  const float* pu = uc  + m0 * DI + e;
  const float* pz = z   + m0 * DI + e;
  const float* px = xdbl + m0 * XD + RK + s * 4;

  float h[4] = {0.f, 0.f, 0.f, 0.f};
  float cp[4] = {1.f, 1.f, 1.f, 1.f};
  float g[4] = {0.f, 0.f, 0.f, 0.f};
  float ssum = 0.f, asum = 0.f;

  for (int t = 0; t < TCH; ++t) {
    float a  = *pd;
    float uu = *pu;
    float zz = *pz;
    float4 bv = *(const float4*)px;
    float4 cv = *(const float4*)(px + NS);
    float gate = zz * fsigmoid(zz);
    float du = a * uu;
    asum += a;
    float bb[4] = {bv.x, bv.y, bv.z, bv.w};
    float cc[4] = {cv.x, cv.y, cv.z, cv.w};
    float y = 0.f;
#pragma unroll
    for (int j = 0; j < 4; ++j) {
      float dA = fexp2(a * Aef[j]);
      h[j] = fmaf(dA, h[j], du * bb[j]);
      cp[j] *= dA;
      g[j] = fmaf(gate * cp[j], cc[j], g[j]);
      y = fmaf(h[j], cc[j], y);
    }
    ssum = fmaf(gate, fmaf(uu, Dv, y), ssum);
    pd += DI; pu += DI; pz += DI; px += XD;
  }

  size_t base = ((size_t)chunk * NS + s * 4) * NCHAN + chan;
#pragma unroll
  for (int j = 0; j < 4; ++j) {
    Pbuf[base + (size_t)j * NCHAN] = fexp2(Aef[j] * asum);
    Hbuf[base + (size_t)j * NCHAN] = h[j];
    Gbuf[base + (size_t)j * NCHAN] = g[j];
  }
  atomicAdd(&sacc[chan], ssum);
}

// ---------------- compose: 1 thread per (chan,state) -------------------------
// Across-chunk recursion is per-state independent; the gate correction
// acc = sum_c G h0 is additive over states -> atomicAdd per (chan,n).
__global__ __launch_bounds__(256) void scan_compose(
    const float* __restrict__ Pbuf, const float* __restrict__ Hbuf,
    const float* __restrict__ Gbuf, float* __restrict__ sacc)
{
  int idx = blockIdx.x * 256 + threadIdx.x;   // NCHAN*NS threads
  int chan = idx & (NCHAN - 1);
  int n = idx >> 12;
  float h0 = 0.f, acc = 0.f;
  size_t o = (size_t)n * NCHAN + chan;
  const size_t step = (size_t)NS * NCHAN;
  for (int c = 0; c < NCH; ++c, o += step) {
    acc = fmaf(Gbuf[o], h0, acc);           // loads are h0-independent
    h0 = fmaf(Pbuf[o], h0, Hbuf[o]);
  }
  atomicAdd(&sacc[chan], acc);
}

// ---------------- out_proj: split-E, atomicAdd into zeroed out ---------------
// grid (DM/64, B_, DI/128), block 64 (one wave).
__global__ __launch_bounds__(64) void out_proj_k(
    const float* __restrict__ s, const float* __restrict__ ow,
    float* __restrict__ out)
{
  int d = blockIdx.x * 64 + threadIdx.x;
  int b = blockIdx.y;
  int e0 = blockIdx.z * 128;
  const float* sb = s + b * DI;
  float acc = 0.f;
  for (int e = e0; e < e0 + 128; ++e)
    acc = fmaf(sb[e], ow[(size_t)e * DM + d], acc);
  atomicAdd(&out[b * DM + d], acc * (1.f / (float)L_));
}

extern "C" void kernel_launch(void* const* d_in, const int* in_sizes, int n_in,
                              void* d_out, int out_size, void* d_ws, size_t ws_size,
                              hipStream_t stream)
{
  const float* x      = (const float*)d_in[0];
  const float* w_proj = (const float*)d_in[1];
  const float* b_proj = (const float*)d_in[2];
  const float* in_w   = (const float*)d_in[3];
  const float* conv_w = (const float*)d_in[4];
  const float* conv_b = (const float*)d_in[5];
  const float* xproj_w= (const float*)d_in[6];
  const float* dt_w   = (const float*)d_in[7];
  const float* dt_b   = (const float*)d_in[8];
  const float* A_log  = (const float*)d_in[9];
  const float* D_skip = (const float*)d_in[10];
  const float* out_w  = (const float*)d_in[11];

  float* ws   = (float*)d_ws;
  float* bufA = ws;
  float* bufZ = bufA + (size_t)M_ * DI;
  float* bufC = bufZ + (size_t)M_ * DI;
  float* xdbl = bufC + (size_t)M_ * DI;
  float* Pb   = xdbl + (size_t)M_ * XD;
  float* Hb   = Pb   + (size_t)NCH * NS * NCHAN;
  float* Gb   = Hb   + (size_t)NCH * NS * NCHAN;
  float* sacc = Gb   + (size_t)NCH * NS * NCHAN;
  unsigned short* wpT_hi = (unsigned short*)(sacc + NCHAN);
  unsigned short* wpT_lo = wpT_hi + (size_t)DIN * DM;
  unsigned short* inT_hi = wpT_lo + (size_t)DIN * DM;
  unsigned short* inT_lo = inT_hi + (size_t)DM * 2 * DI;
  unsigned short* xpT_hi = inT_lo + (size_t)DM * 2 * DI;
  unsigned short* xpT_lo = xpT_hi + (size_t)DI * XD;

  unsigned short* h_hi = (unsigned short*)bufC;
  unsigned short* h_lo = h_hi + (size_t)M_ * DM;
  float* u    = bufA;
  float* z    = bufZ;
  float* uc   = bufC;
  float* dtv  = bufA;
  float* xpart = Pb;

  // 0. weight prep (LDS-tiled transpose+split)
  transpose_split<<<dim3(DIN / 32, DM / 32), 256, 0, stream>>>(w_proj, DIN, DM, wpT_hi, wpT_lo);
  transpose_split<<<dim3(DM / 32, 2 * DI / 32), 256, 0, stream>>>(in_w, DM, 2 * DI, inT_hi, inT_lo);
  transpose_split<<<dim3(DI / 32, XD / 32), 256, 0, stream>>>(xproj_w, DI, XD, xpT_hi, xpT_lo);

  // 1. h = x @ w_proj + b_proj  -> split bf16 pair  [M, DM]
  gemm_in<<<dim3(DM / 128, M_ / 128), 256, 0, stream>>>(
      x, wpT_hi, wpT_lo, b_proj, h_hi, h_lo, M_, DM, DIN, DM);
  // 2. (u|z) = h @ in_w, one launch                 [M, 2048] -> u,z [M,DI]
  gemm_presplit3<<<dim3(2 * DI / 128, M_ / 128), 256, 0, stream>>>(
      h_hi, h_lo, inT_hi, inT_lo, u, z, M_, 2 * DI, DM, DI, DI);
  // 3. uc = silu(causal_dwconv(u) + conv_b)
  conv_silu<<<(M_ * DI) / 256, 256, 0, stream>>>(u, conv_w, conv_b, uc);
  // 4. xdbl = uc @ xproj_w, split-K=4               [M, 64]
  gemm_splitk<<<dim3(1, M_ / 64, 4), 256, 0, stream>>>(
      uc, xpT_hi, xpT_lo, xpart, M_, XD, DI, DI / 4);
  xreduce<<<(M_ * XD) / 1024, 256, 0, stream>>>(xpart, xdbl);
  // 5. dtv = softplus(dt_raw @ dt_w + dt_b)
  dtproj_k<<<(M_ * DI) / 256, 256, 0, stream>>>(xdbl, dt_w, dt_b, dtv);
  // 6. fused single-pass chunked scan
  hipMemsetAsync(sacc, 0, NCHAN * sizeof(float), stream);
  scan_fused<<<dim3(NCHAN / 64, NCH), 256, 0, stream>>>(
      dtv, uc, xdbl, A_log, z, D_skip, Pb, Hb, Gb, sacc);
  // 7. compose boundaries + corrections (1 thread per chan,state)
  scan_compose<<<(NCHAN * NS) / 256, 256, 0, stream>>>(Pb, Hb, Gb, sacc);
  // 8. out = (s/L) @ out_w  (split-E + atomics into zeroed out)
  hipMemsetAsync(d_out, 0, (size_t)out_size * sizeof(float), stream);
  out_proj_k<<<dim3(DM / 64, B_, DI / 128), 64, 0, stream>>>(
      sacc, out_w, (float*)d_out);
}

// Round 7
// 570.656 us; speedup vs baseline: 2.7601x; 1.0617x over previous
//
#include <hip/hip_runtime.h>
#include <cstdint>
#include <cstddef>

// Mamba backbone fwd: B=4, L=4096, IN=256, DM=512, DI=1024, N=16, R=32.
// Round 7: ALGEBRAIC FUSION — xz = x@(W1@W2) + b1@W2. W12 precomputed per
// call (0.27 GFMA); big GEMM is now M x 2048 x 256 (2.24x fewer FLOPs than
// input_proj+in_proj), pure glds staging on pre-split x. gemm_in eliminated.
// gemm_splitk atomics into zeroed xdbl (xreduce eliminated).

#define B_    4
#define L_    4096
#define M_    (B_ * L_)        // 16384 rows
#define DIN   256
#define DM    512
#define DI    1024
#define NS    16
#define RK    32
#define XD    64               // RK + 2*NS
#define TCH   128              // scan chunk length
#define NCH   (L_ / TCH)       // 32 chunks
#define NCHAN (B_ * DI)        // 4096 scalar channels

#define L2E   1.44269504088896f
#define LN2   0.69314718055995f

typedef __bf16 bf16_t;
typedef bf16_t bf16x8 __attribute__((ext_vector_type(8)));
typedef float  f32x4  __attribute__((ext_vector_type(4)));

static __device__ __forceinline__ float fexp2(float x)  { return __builtin_amdgcn_exp2f(x); }
static __device__ __forceinline__ float frcp(float x)   { return __builtin_amdgcn_rcpf(x); }
static __device__ __forceinline__ float flog2(float x)  { return __builtin_amdgcn_logf(x); }
static __device__ __forceinline__ float fsigmoid(float x) {
  return frcp(1.f + fexp2(-x * L2E));
}

static __device__ __forceinline__ unsigned short f32_to_bf16_rne(float f) {
  unsigned u = __float_as_uint(f);
  u += 0x7fffu + ((u >> 16) & 1u);
  return (unsigned short)(u >> 16);
}
static __device__ __forceinline__ float bf16_to_f32(unsigned short h) {
  return __uint_as_float(((unsigned)h) << 16);
}

// async global->LDS, 16 B per lane; LDS dst = wave-uniform base + lane*16.
typedef __attribute__((address_space(1))) const unsigned int ga_u32;
typedef __attribute__((address_space(3))) unsigned int ls_u32;
static __device__ __forceinline__ void glds16(const void* g, void* l) {
  __builtin_amdgcn_global_load_lds((ga_u32*)g, (ls_u32*)l, 16, 0, 0);
}

// ---- LDS-tiled transpose + split: W[K][N] -> T_hi/lo [N][K] ----------------
__global__ __launch_bounds__(256) void transpose_split(
    const float* __restrict__ W, int K, int N,
    unsigned short* __restrict__ Thi, unsigned short* __restrict__ Tlo)
{
  __shared__ float tile[32][33];
  const int kt = blockIdx.x * 32, nt = blockIdx.y * 32;
  const int tx = threadIdx.x & 31, ty = threadIdx.x >> 5;
#pragma unroll
  for (int i = ty; i < 32; i += 8)
    tile[i][tx] = W[(size_t)(kt + i) * N + nt + tx];
  __syncthreads();
#pragma unroll
  for (int i = ty; i < 32; i += 8) {
    float f = tile[tx][i];
    unsigned short hi = f32_to_bf16_rne(f);
    size_t o = (size_t)(nt + i) * K + kt + tx;
    Thi[o] = hi;
    Tlo[o] = f32_to_bf16_rne(f - bf16_to_f32(hi));
  }
}

// ---- elementwise split: X fp32 -> (hi,lo) bf16 (no transpose) --------------
__global__ __launch_bounds__(256) void split_pair(
    const float* __restrict__ X, unsigned short* __restrict__ Hi,
    unsigned short* __restrict__ Lo, int count4)
{
  int i = blockIdx.x * 256 + threadIdx.x;
  if (i >= count4) return;
  float4 v = *(const float4*)(X + (size_t)i * 4);
  unsigned short h0 = f32_to_bf16_rne(v.x), h1 = f32_to_bf16_rne(v.y);
  unsigned short h2 = f32_to_bf16_rne(v.z), h3 = f32_to_bf16_rne(v.w);
  *(ushort4*)(Hi + (size_t)i * 4) = make_ushort4(h0, h1, h2, h3);
  *(ushort4*)(Lo + (size_t)i * 4) =
      make_ushort4(f32_to_bf16_rne(v.x - bf16_to_f32(h0)),
                   f32_to_bf16_rne(v.y - bf16_to_f32(h1)),
                   f32_to_bf16_rne(v.z - bf16_to_f32(h2)),
                   f32_to_bf16_rne(v.w - bf16_to_f32(h3)));
}

// ---- bias2[n] = sum_k b_proj[k] * in_w[k][n],  n in [0,2048) ---------------
__global__ __launch_bounds__(256) void bias2_k(
    const float* __restrict__ bp, const float* __restrict__ inw,
    float* __restrict__ bias2)
{
  int n = blockIdx.x * 256 + threadIdx.x;
  float acc = 0.f;
  for (int k = 0; k < DM; ++k)
    acc = fmaf(bp[k], inw[(size_t)k * (2 * DI) + n], acc);
  bias2[n] = acc;
}

// ---- split-bf16 3-MFMA GEMM, pre-split A & B, glds staging -----------------
// 128x128 tile, BK=32, 4 waves (2x2 of 64x64). Subtile = 16r x 32k = 1024 B.
// OUTMODE 0: fp32 out, columns >= splitN go to O2 (+bias).
// OUTMODE 1: bf16 (hi,lo) pair out (O1=hi, O2=lo).
template<int OUTMODE>
__global__ __launch_bounds__(256) void gemm_ps3(
    const unsigned short* __restrict__ Ahi, const unsigned short* __restrict__ Alo,
    const unsigned short* __restrict__ Bhi, const unsigned short* __restrict__ Blo,
    const float* __restrict__ bias, void* __restrict__ O1, void* __restrict__ O2,
    int M, int N, int K, int ldc, int splitN)
{
  __shared__ __align__(16) unsigned short lA[2][8 * 512];
  __shared__ __align__(16) unsigned short lB[2][8 * 512];
  const int tid = threadIdx.x, wave = tid >> 6, lane = tid & 63;
  const int r = lane & 15, kq = lane >> 4;
  const int bm0 = blockIdx.y * 128, bn0 = blockIdx.x * 128;
  const int wm = (wave >> 1) * 4, wn = (wave & 1) * 4;
  const int s0 = wave * 2;

  const unsigned short* gAh = Ahi + (size_t)(bm0 + s0 * 16 + r) * K + kq * 8;
  const unsigned short* gAl = Alo + (size_t)(bm0 + s0 * 16 + r) * K + kq * 8;
  const unsigned short* gBh = Bhi + (size_t)(bn0 + s0 * 16 + r) * K + kq * 8;
  const unsigned short* gBl = Blo + (size_t)(bn0 + s0 * 16 + r) * K + kq * 8;
  const size_t rowK16 = (size_t)16 * K;

  f32x4 acc[4][4];
#pragma unroll
  for (int i = 0; i < 4; ++i)
#pragma unroll
    for (int j = 0; j < 4; ++j) acc[i][j] = 0.f;

  for (int k0 = 0; k0 < K; k0 += 32) {
    glds16(gAh,          &lA[0][s0 * 512]);
    glds16(gAh + rowK16, &lA[0][(s0 + 1) * 512]);
    glds16(gAl,          &lA[1][s0 * 512]);
    glds16(gAl + rowK16, &lA[1][(s0 + 1) * 512]);
    glds16(gBh,          &lB[0][s0 * 512]);
    glds16(gBh + rowK16, &lB[0][(s0 + 1) * 512]);
    glds16(gBl,          &lB[1][s0 * 512]);
    glds16(gBl + rowK16, &lB[1][(s0 + 1) * 512]);
    gAh += 32; gAl += 32; gBh += 32; gBl += 32;
    __syncthreads();
    bf16x8 ah[4], al[4];
#pragma unroll
    for (int i = 0; i < 4; ++i) {
      ah[i] = *(const bf16x8*)&lA[0][(wm + i) * 512 + lane * 8];
      al[i] = *(const bf16x8*)&lA[1][(wm + i) * 512 + lane * 8];
    }
#pragma unroll
    for (int j = 0; j < 4; ++j) {
      bf16x8 bh = *(const bf16x8*)&lB[0][(wn + j) * 512 + lane * 8];
      bf16x8 bl = *(const bf16x8*)&lB[1][(wn + j) * 512 + lane * 8];
#pragma unroll
      for (int i = 0; i < 4; ++i) {
        acc[i][j] = __builtin_amdgcn_mfma_f32_16x16x32_bf16(ah[i], bh, acc[i][j], 0, 0, 0);
        acc[i][j] = __builtin_amdgcn_mfma_f32_16x16x32_bf16(ah[i], bl, acc[i][j], 0, 0, 0);
        acc[i][j] = __builtin_amdgcn_mfma_f32_16x16x32_bf16(al[i], bh, acc[i][j], 0, 0, 0);
      }
    }
    __syncthreads();
  }
  // epilogue: C/D col=lane&15 (=r), row=kq*4+reg
#pragma unroll
  for (int j = 0; j < 4; ++j) {
    int gc = bn0 + (wn + j) * 16 + r;
    if constexpr (OUTMODE == 0) {
      float bv = bias ? bias[gc] : 0.f;
      float* dst = (gc < splitN) ? ((float*)O1 + gc) : ((float*)O2 + gc - splitN);
#pragma unroll
      for (int i = 0; i < 4; ++i) {
        int gr = bm0 + (wm + i) * 16 + kq * 4;
#pragma unroll
        for (int rr = 0; rr < 4; ++rr)
          dst[(size_t)(gr + rr) * ldc] = acc[i][j][rr] + bv;
      }
    } else {
      unsigned short* Chi = (unsigned short*)O1;
      unsigned short* Clo = (unsigned short*)O2;
#pragma unroll
      for (int i = 0; i < 4; ++i) {
        int gr = bm0 + (wm + i) * 16 + kq * 4;
#pragma unroll
        for (int rr = 0; rr < 4; ++rr) {
          float v = acc[i][j][rr];
          unsigned short hi = f32_to_bf16_rne(v);
          Chi[(size_t)(gr + rr) * ldc + gc] = hi;
          Clo[(size_t)(gr + rr) * ldc + gc] = f32_to_bf16_rne(v - bf16_to_f32(hi));
        }
      }
    }
  }
}

// ---- xproj split-K: A fp32 on-the-fly, 64x64 tile, atomics into xdbl -------
__global__ __launch_bounds__(256) void gemm_splitk(
    const float* __restrict__ A, const unsigned short* __restrict__ Bhi,
    const unsigned short* __restrict__ Blo, float* __restrict__ Cacc,
    int M, int N, int K, int kslice)
{
  constexpr int BM = 64, BN = 64, PAD = 40;
  __shared__ unsigned short lAhi[BM * PAD];
  __shared__ unsigned short lAlo[BM * PAD];
  __shared__ unsigned short lBhi[BN * PAD];
  __shared__ unsigned short lBlo[BN * PAD];
  const int tid  = threadIdx.x;
  const int wave = tid >> 6, lane = tid & 63;
  const int wm0 = (wave >> 1) * 32, wn0 = (wave & 1) * 32;
  const int bm0 = blockIdx.y * BM, bn0 = blockIdx.x * BN;
  const int kz  = blockIdx.z;
  const int sr = tid >> 3, sc = (tid & 7) << 2;
  const int fm = lane & 15, fq = lane >> 4;

  f32x4 acc[2][2];
#pragma unroll
  for (int i = 0; i < 2; ++i)
#pragma unroll
    for (int j = 0; j < 2; ++j) acc[i][j] = 0.f;

  const int kbeg = kz * kslice, kend = kbeg + kslice;
  for (int k0 = kbeg; k0 < kend; k0 += 32) {
#pragma unroll
    for (int r = sr; r < BM; r += 32) {
      float4 v = *(const float4*)(A + (size_t)(bm0 + r) * K + k0 + sc);
      unsigned short h0 = f32_to_bf16_rne(v.x), h1 = f32_to_bf16_rne(v.y);
      unsigned short h2 = f32_to_bf16_rne(v.z), h3 = f32_to_bf16_rne(v.w);
      *(ushort4*)&lAhi[r * PAD + sc] = make_ushort4(h0, h1, h2, h3);
      *(ushort4*)&lAlo[r * PAD + sc] =
          make_ushort4(f32_to_bf16_rne(v.x - bf16_to_f32(h0)),
                       f32_to_bf16_rne(v.y - bf16_to_f32(h1)),
                       f32_to_bf16_rne(v.z - bf16_to_f32(h2)),
                       f32_to_bf16_rne(v.w - bf16_to_f32(h3)));
    }
#pragma unroll
    for (int r = sr; r < BN; r += 32) {
      *(ushort4*)&lBhi[r * PAD + sc] =
          *(const ushort4*)(Bhi + (size_t)(bn0 + r) * K + k0 + sc);
      *(ushort4*)&lBlo[r * PAD + sc] =
          *(const ushort4*)(Blo + (size_t)(bn0 + r) * K + k0 + sc);
    }
    __syncthreads();
    bf16x8 ah[2], al[2];
#pragma unroll
    for (int i = 0; i < 2; ++i) {
      int row = wm0 + i * 16 + fm;
      ah[i] = *(const bf16x8*)&lAhi[row * PAD + fq * 8];
      al[i] = *(const bf16x8*)&lAlo[row * PAD + fq * 8];
    }
#pragma unroll
    for (int j = 0; j < 2; ++j) {
      int col = wn0 + j * 16 + fm;
      bf16x8 bh = *(const bf16x8*)&lBhi[col * PAD + fq * 8];
      bf16x8 bl = *(const bf16x8*)&lBlo[col * PAD + fq * 8];
#pragma unroll
      for (int i = 0; i < 2; ++i) {
        acc[i][j] = __builtin_amdgcn_mfma_f32_16x16x32_bf16(ah[i], bh, acc[i][j], 0, 0, 0);
        acc[i][j] = __builtin_amdgcn_mfma_f32_16x16x32_bf16(ah[i], bl, acc[i][j], 0, 0, 0);
        acc[i][j] = __builtin_amdgcn_mfma_f32_16x16x32_bf16(al[i], bh, acc[i][j], 0, 0, 0);
      }
    }
    __syncthreads();
  }
#pragma unroll
  for (int j = 0; j < 2; ++j) {
    int gc = bn0 + wn0 + j * 16 + fm;
#pragma unroll
    for (int i = 0; i < 2; ++i) {
      int gr = bm0 + wm0 + i * 16 + fq * 4;
#pragma unroll
      for (int rr = 0; rr < 4; ++rr)
        atomicAdd(&Cacc[(size_t)(gr + rr) * N + gc], acc[i][j][rr]);
    }
  }
}

// ---------------- depthwise causal conv1d (4 taps) + silu --------------------
__global__ __launch_bounds__(256) void conv_silu(
    const float* __restrict__ u, const float* __restrict__ cw,
    const float* __restrict__ cb, float* __restrict__ uc)
{
  int idx = blockIdx.x * 256 + threadIdx.x;
  int e = idx & (DI - 1);
  int m = idx >> 10;
  int t = m & (L_ - 1);
  const float* w = cw + e * 4;
  float acc = cb[e];
#pragma unroll
  for (int k = 0; k < 4; ++k) {
    int tt = t - 3 + k;
    if (tt >= 0) acc += u[(size_t)(m - 3 + k) * DI + e] * w[k];
  }
  uc[idx] = acc * fsigmoid(acc);
}

// ---------------- dt_proj + softplus: dtv[M,DI] ------------------------------
__global__ __launch_bounds__(256) void dtproj_k(
    const float* __restrict__ xdbl, const float* __restrict__ dtw,
    const float* __restrict__ dtb, float* __restrict__ dtv)
{
  int idx = blockIdx.x * 256 + threadIdx.x;
  int e = idx & (DI - 1);
  int m = idx >> 10;
  const float* xr = xdbl + (size_t)m * XD;
  float acc = dtb[e];
#pragma unroll
  for (int k = 0; k < RK; ++k) acc += xr[k] * dtw[k * DI + e];
  float t = fexp2(-fabsf(acc) * L2E);
  dtv[idx] = fmaxf(acc, 0.f) + flog2(1.f + t) * LN2;
}

// ---------------- fused scan: local scan + S_loc + (P,H,G) per chunk ---------
__global__ __launch_bounds__(256) void scan_fused(
    const float* __restrict__ dtv, const float* __restrict__ uc,
    const float* __restrict__ xdbl, const float* __restrict__ A_log,
    const float* __restrict__ z, const float* __restrict__ Dsk,
    float* __restrict__ Pbuf, float* __restrict__ Hbuf,
    float* __restrict__ Gbuf, float* __restrict__ sacc)
{
  const int l = threadIdx.x & 63;
  const int s = threadIdx.x >> 6;
  const int chan = blockIdx.x * 64 + l;
  const int e = chan & (DI - 1);
  const int b = chan >> 10;
  const int chunk = blockIdx.y;

  float Aef[4];
#pragma unroll
  for (int j = 0; j < 4; ++j)
    Aef[j] = -__expf(A_log[e * NS + s * 4 + j]) * L2E;
  const float Dv = (s == 0) ? Dsk[e] : 0.f;

  size_t m0 = (size_t)b * L_ + (size_t)chunk * TCH;
  const float* pd = dtv + m0 * DI + e;
  const float* pu = uc  + m0 * DI + e;
  const float* pz = z   + m0 * DI + e;
  const float* px = xdbl + m0 * XD + RK + s * 4;

  float h[4] = {0.f, 0.f, 0.f, 0.f};
  float cp[4] = {1.f, 1.f, 1.f, 1.f};
  float g[4] = {0.f, 0.f, 0.f, 0.f};
  float ssum = 0.f, asum = 0.f;

  for (int t = 0; t < TCH; ++t) {
    float a  = *pd;
    float uu = *pu;
    float zz = *pz;
    float4 bv = *(const float4*)px;
    float4 cv = *(const float4*)(px + NS);
    float gate = zz * fsigmoid(zz);
    float du = a * uu;
    asum += a;
    float bb[4] = {bv.x, bv.y, bv.z, bv.w};
    float cc[4] = {cv.x, cv.y, cv.z, cv.w};
    float y = 0.f;
#pragma unroll
    for (int j = 0; j < 4; ++j) {
      float dA = fexp2(a * Aef[j]);
      h[j] = fmaf(dA, h[j], du * bb[j]);
      cp[j] *= dA;
      g[j] = fmaf(gate * cp[j], cc[j], g[j]);
      y = fmaf(h[j], cc[j], y);
    }
    ssum = fmaf(gate, fmaf(uu, Dv, y), ssum);
    pd += DI; pu += DI; pz += DI; px += XD;
  }

  size_t base = ((size_t)chunk * NS + s * 4) * NCHAN + chan;
#pragma unroll
  for (int j = 0; j < 4; ++j) {
    Pbuf[base + (size_t)j * NCHAN] = fexp2(Aef[j] * asum);
    Hbuf[base + (size_t)j * NCHAN] = h[j];
    Gbuf[base + (size_t)j * NCHAN] = g[j];
  }
  atomicAdd(&sacc[chan], ssum);
}

// ---------------- compose: 1 thread per (chan,state) -------------------------
__global__ __launch_bounds__(256) void scan_compose(
    const float* __restrict__ Pbuf, const float* __restrict__ Hbuf,
    const float* __restrict__ Gbuf, float* __restrict__ sacc)
{
  int idx = blockIdx.x * 256 + threadIdx.x;   // NCHAN*NS threads
  int chan = idx & (NCHAN - 1);
  int n = idx >> 12;
  float h0 = 0.f, acc = 0.f;
  size_t o = (size_t)n * NCHAN + chan;
  const size_t step = (size_t)NS * NCHAN;
  for (int c = 0; c < NCH; ++c, o += step) {
    acc = fmaf(Gbuf[o], h0, acc);
    h0 = fmaf(Pbuf[o], h0, Hbuf[o]);
  }
  atomicAdd(&sacc[chan], acc);
}

// ---------------- out_proj: split-E, atomicAdd into zeroed out ---------------
__global__ __launch_bounds__(64) void out_proj_k(
    const float* __restrict__ s, const float* __restrict__ ow,
    float* __restrict__ out)
{
  int d = blockIdx.x * 64 + threadIdx.x;
  int b = blockIdx.y;
  int e0 = blockIdx.z * 128;
  const float* sb = s + b * DI;
  float acc = 0.f;
  for (int e = e0; e < e0 + 128; ++e)
    acc = fmaf(sb[e], ow[(size_t)e * DM + d], acc);
  atomicAdd(&out[b * DM + d], acc * (1.f / (float)L_));
}

extern "C" void kernel_launch(void* const* d_in, const int* in_sizes, int n_in,
                              void* d_out, int out_size, void* d_ws, size_t ws_size,
                              hipStream_t stream)
{
  const float* x      = (const float*)d_in[0];
  const float* w_proj = (const float*)d_in[1];
  const float* b_proj = (const float*)d_in[2];
  const float* in_w   = (const float*)d_in[3];
  const float* conv_w = (const float*)d_in[4];
  const float* conv_b = (const float*)d_in[5];
  const float* xproj_w= (const float*)d_in[6];
  const float* dt_w   = (const float*)d_in[7];
  const float* dt_b   = (const float*)d_in[8];
  const float* A_log  = (const float*)d_in[9];
  const float* D_skip = (const float*)d_in[10];
  const float* out_w  = (const float*)d_in[11];

  // Workspace (~238 MB): bufA: u -> dtv; bufZ: z; bufC: x-pair -> uc.
  float* ws   = (float*)d_ws;
  float* bufA = ws;
  float* bufZ = bufA + (size_t)M_ * DI;
  float* bufC = bufZ + (size_t)M_ * DI;
  float* xdbl = bufC + (size_t)M_ * DI;              // M*64
  float* Pb   = xdbl + (size_t)M_ * XD;
  float* Hb   = Pb   + (size_t)NCH * NS * NCHAN;
  float* Gb   = Hb   + (size_t)NCH * NS * NCHAN;
  float* sacc = Gb   + (size_t)NCH * NS * NCHAN;     // 4096 f
  unsigned short* inT_hi = (unsigned short*)(sacc + NCHAN);  // [2048][512]
  unsigned short* inT_lo = inT_hi + (size_t)2 * DI * DM;
  unsigned short* wp_hi  = inT_lo + (size_t)2 * DI * DM;     // [256][512]
  unsigned short* wp_lo  = wp_hi  + (size_t)DIN * DM;
  unsigned short* w12_hi = wp_lo  + (size_t)DIN * DM;        // [2048][256]
  unsigned short* w12_lo = w12_hi + (size_t)2 * DI * DIN;
  unsigned short* xpT_hi = w12_lo + (size_t)2 * DI * DIN;    // [64][1024]
  unsigned short* xpT_lo = xpT_hi + (size_t)XD * DI;
  float* bias2 = (float*)(xpT_lo + (size_t)XD * DI);         // [2048]

  unsigned short* x_hi = (unsigned short*)bufC;      // [M][256] pair
  unsigned short* x_lo = x_hi + (size_t)M_ * DIN;
  float* u    = bufA;
  float* z    = bufZ;
  float* uc   = bufC;                                // overwrites x-pair (dead)
  float* dtv  = bufA;                                // overwrites u (dead)

  // 0. weight prep
  transpose_split<<<dim3(DM / 32, 2 * DI / 32), 256, 0, stream>>>(
      in_w, DM, 2 * DI, inT_hi, inT_lo);
  transpose_split<<<dim3(DI / 32, XD / 32), 256, 0, stream>>>(
      xproj_w, DI, XD, xpT_hi, xpT_lo);
  split_pair<<<(DIN * DM / 4 + 255) / 256, 256, 0, stream>>>(
      w_proj, wp_hi, wp_lo, DIN * DM / 4);
  split_pair<<<(M_ * DIN / 4 + 255) / 256, 256, 0, stream>>>(
      x, x_hi, x_lo, M_ * DIN / 4);
  // 0b. W12T[2048][256] = inT @ w_proj  (= (W1@W2)^T), bf16-pair output
  gemm_ps3<1><<<dim3(DIN / 128, 2 * DI / 128), 256, 0, stream>>>(
      inT_hi, inT_lo, wp_hi, wp_lo, nullptr, w12_hi, w12_lo,
      2 * DI, DIN, DM, DIN, DIN);
  // 0c. bias2 = b_proj @ in_w
  bias2_k<<<2 * DI / 256, 256, 0, stream>>>(b_proj, in_w, bias2);

  // 1. (u|z) = x @ W12 + bias2  (fused input_proj+in_proj)  [M,2048]
  gemm_ps3<0><<<dim3(2 * DI / 128, M_ / 128), 256, 0, stream>>>(
      x_hi, x_lo, w12_hi, w12_lo, bias2, u, z, M_, 2 * DI, DIN, DI, DI);
  // 2. uc = silu(causal_dwconv(u) + conv_b)   (overwrites x-pair; dead)
  conv_silu<<<(M_ * DI) / 256, 256, 0, stream>>>(u, conv_w, conv_b, uc);
  // 3. xdbl = uc @ xproj_w, split-K=4 atomics  [M, 64]
  hipMemsetAsync(xdbl, 0, (size_t)M_ * XD * sizeof(float), stream);
  gemm_splitk<<<dim3(1, M_ / 64, 4), 256, 0, stream>>>(
      uc, xpT_hi, xpT_lo, xdbl, M_, XD, DI, DI / 4);
  // 4. dtv = softplus(dt_raw @ dt_w + dt_b)   (overwrites u; dead)
  dtproj_k<<<(M_ * DI) / 256, 256, 0, stream>>>(xdbl, dt_w, dt_b, dtv);
  // 5. fused single-pass chunked scan
  hipMemsetAsync(sacc, 0, NCHAN * sizeof(float), stream);
  scan_fused<<<dim3(NCHAN / 64, NCH), 256, 0, stream>>>(
      dtv, uc, xdbl, A_log, z, D_skip, Pb, Hb, Gb, sacc);
  // 6. compose boundaries + corrections
  scan_compose<<<(NCHAN * NS) / 256, 256, 0, stream>>>(Pb, Hb, Gb, sacc);
  // 7. out = (s/L) @ out_w
  hipMemsetAsync(d_out, 0, (size_t)out_size * sizeof(float), stream);
  out_proj_k<<<dim3(DM / 64, B_, DI / 128), 64, 0, stream>>>(
      sacc, out_w, (float*)d_out);
}

// Round 8
// 471.413 us; speedup vs baseline: 3.3411x; 1.2105x over previous
//
#include <hip/hip_runtime.h>
#include <cstdint>
#include <cstddef>

// Mamba backbone fwd: B=4, L=4096, IN=256, DM=512, DI=1024, N=16, R=32.
// Round 8: dtproj rebuilt as a single-shot K=32 MFMA GEMM (gemm_dt) with
// bias+softplus fused in the epilogue (was a 131 us scalar kernel at 4 TF;
// floor is the 67 MB dtv write ~ 12 us). dt_w pre-transposed+split.
// Everything else unchanged from round 7 (fused x@(W1@W2) GEMM etc).

#define B_    4
#define L_    4096
#define M_    (B_ * L_)        // 16384 rows
#define DIN   256
#define DM    512
#define DI    1024
#define NS    16
#define RK    32
#define XD    64               // RK + 2*NS
#define TCH   128              // scan chunk length
#define NCH   (L_ / TCH)       // 32 chunks
#define NCHAN (B_ * DI)        // 4096 scalar channels

#define L2E   1.44269504088896f
#define LN2   0.69314718055995f

typedef __bf16 bf16_t;
typedef bf16_t bf16x8 __attribute__((ext_vector_type(8)));
typedef float  f32x4  __attribute__((ext_vector_type(4)));

static __device__ __forceinline__ float fexp2(float x)  { return __builtin_amdgcn_exp2f(x); }
static __device__ __forceinline__ float frcp(float x)   { return __builtin_amdgcn_rcpf(x); }
static __device__ __forceinline__ float flog2(float x)  { return __builtin_amdgcn_logf(x); }
static __device__ __forceinline__ float fsigmoid(float x) {
  return frcp(1.f + fexp2(-x * L2E));
}

static __device__ __forceinline__ unsigned short f32_to_bf16_rne(float f) {
  unsigned u = __float_as_uint(f);
  u += 0x7fffu + ((u >> 16) & 1u);
  return (unsigned short)(u >> 16);
}
static __device__ __forceinline__ float bf16_to_f32(unsigned short h) {
  return __uint_as_float(((unsigned)h) << 16);
}

// async global->LDS, 16 B per lane; LDS dst = wave-uniform base + lane*16.
typedef __attribute__((address_space(1))) const unsigned int ga_u32;
typedef __attribute__((address_space(3))) unsigned int ls_u32;
static __device__ __forceinline__ void glds16(const void* g, void* l) {
  __builtin_amdgcn_global_load_lds((ga_u32*)g, (ls_u32*)l, 16, 0, 0);
}

// ---- LDS-tiled transpose + split: W[K][N] -> T_hi/lo [N][K] ----------------
__global__ __launch_bounds__(256) void transpose_split(
    const float* __restrict__ W, int K, int N,
    unsigned short* __restrict__ Thi, unsigned short* __restrict__ Tlo)
{
  __shared__ float tile[32][33];
  const int kt = blockIdx.x * 32, nt = blockIdx.y * 32;
  const int tx = threadIdx.x & 31, ty = threadIdx.x >> 5;
#pragma unroll
  for (int i = ty; i < 32; i += 8)
    tile[i][tx] = W[(size_t)(kt + i) * N + nt + tx];
  __syncthreads();
#pragma unroll
  for (int i = ty; i < 32; i += 8) {
    float f = tile[tx][i];
    unsigned short hi = f32_to_bf16_rne(f);
    size_t o = (size_t)(nt + i) * K + kt + tx;
    Thi[o] = hi;
    Tlo[o] = f32_to_bf16_rne(f - bf16_to_f32(hi));
  }
}

// ---- elementwise split: X fp32 -> (hi,lo) bf16 (no transpose) --------------
__global__ __launch_bounds__(256) void split_pair(
    const float* __restrict__ X, unsigned short* __restrict__ Hi,
    unsigned short* __restrict__ Lo, int count4)
{
  int i = blockIdx.x * 256 + threadIdx.x;
  if (i >= count4) return;
  float4 v = *(const float4*)(X + (size_t)i * 4);
  unsigned short h0 = f32_to_bf16_rne(v.x), h1 = f32_to_bf16_rne(v.y);
  unsigned short h2 = f32_to_bf16_rne(v.z), h3 = f32_to_bf16_rne(v.w);
  *(ushort4*)(Hi + (size_t)i * 4) = make_ushort4(h0, h1, h2, h3);
  *(ushort4*)(Lo + (size_t)i * 4) =
      make_ushort4(f32_to_bf16_rne(v.x - bf16_to_f32(h0)),
                   f32_to_bf16_rne(v.y - bf16_to_f32(h1)),
                   f32_to_bf16_rne(v.z - bf16_to_f32(h2)),
                   f32_to_bf16_rne(v.w - bf16_to_f32(h3)));
}

// ---- bias2[n] = sum_k b_proj[k] * in_w[k][n],  n in [0,2048) ---------------
__global__ __launch_bounds__(256) void bias2_k(
    const float* __restrict__ bp, const float* __restrict__ inw,
    float* __restrict__ bias2)
{
  int n = blockIdx.x * 256 + threadIdx.x;
  float acc = 0.f;
  for (int k = 0; k < DM; ++k)
    acc = fmaf(bp[k], inw[(size_t)k * (2 * DI) + n], acc);
  bias2[n] = acc;
}

// ---- split-bf16 3-MFMA GEMM, pre-split A & B, glds staging -----------------
// 128x128 tile, BK=32, 4 waves (2x2 of 64x64). Subtile = 16r x 32k = 1024 B.
// OUTMODE 0: fp32 out, columns >= splitN go to O2 (+bias).
// OUTMODE 1: bf16 (hi,lo) pair out (O1=hi, O2=lo).
template<int OUTMODE>
__global__ __launch_bounds__(256) void gemm_ps3(
    const unsigned short* __restrict__ Ahi, const unsigned short* __restrict__ Alo,
    const unsigned short* __restrict__ Bhi, const unsigned short* __restrict__ Blo,
    const float* __restrict__ bias, void* __restrict__ O1, void* __restrict__ O2,
    int M, int N, int K, int ldc, int splitN)
{
  __shared__ __align__(16) unsigned short lA[2][8 * 512];
  __shared__ __align__(16) unsigned short lB[2][8 * 512];
  const int tid = threadIdx.x, wave = tid >> 6, lane = tid & 63;
  const int r = lane & 15, kq = lane >> 4;
  const int bm0 = blockIdx.y * 128, bn0 = blockIdx.x * 128;
  const int wm = (wave >> 1) * 4, wn = (wave & 1) * 4;
  const int s0 = wave * 2;

  const unsigned short* gAh = Ahi + (size_t)(bm0 + s0 * 16 + r) * K + kq * 8;
  const unsigned short* gAl = Alo + (size_t)(bm0 + s0 * 16 + r) * K + kq * 8;
  const unsigned short* gBh = Bhi + (size_t)(bn0 + s0 * 16 + r) * K + kq * 8;
  const unsigned short* gBl = Blo + (size_t)(bn0 + s0 * 16 + r) * K + kq * 8;
  const size_t rowK16 = (size_t)16 * K;

  f32x4 acc[4][4];
#pragma unroll
  for (int i = 0; i < 4; ++i)
#pragma unroll
    for (int j = 0; j < 4; ++j) acc[i][j] = 0.f;

  for (int k0 = 0; k0 < K; k0 += 32) {
    glds16(gAh,          &lA[0][s0 * 512]);
    glds16(gAh + rowK16, &lA[0][(s0 + 1) * 512]);
    glds16(gAl,          &lA[1][s0 * 512]);
    glds16(gAl + rowK16, &lA[1][(s0 + 1) * 512]);
    glds16(gBh,          &lB[0][s0 * 512]);
    glds16(gBh + rowK16, &lB[0][(s0 + 1) * 512]);
    glds16(gBl,          &lB[1][s0 * 512]);
    glds16(gBl + rowK16, &lB[1][(s0 + 1) * 512]);
    gAh += 32; gAl += 32; gBh += 32; gBl += 32;
    __syncthreads();
    bf16x8 ah[4], al[4];
#pragma unroll
    for (int i = 0; i < 4; ++i) {
      ah[i] = *(const bf16x8*)&lA[0][(wm + i) * 512 + lane * 8];
      al[i] = *(const bf16x8*)&lA[1][(wm + i) * 512 + lane * 8];
    }
#pragma unroll
    for (int j = 0; j < 4; ++j) {
      bf16x8 bh = *(const bf16x8*)&lB[0][(wn + j) * 512 + lane * 8];
      bf16x8 bl = *(const bf16x8*)&lB[1][(wn + j) * 512 + lane * 8];
#pragma unroll
      for (int i = 0; i < 4; ++i) {
        acc[i][j] = __builtin_amdgcn_mfma_f32_16x16x32_bf16(ah[i], bh, acc[i][j], 0, 0, 0);
        acc[i][j] = __builtin_amdgcn_mfma_f32_16x16x32_bf16(ah[i], bl, acc[i][j], 0, 0, 0);
        acc[i][j] = __builtin_amdgcn_mfma_f32_16x16x32_bf16(al[i], bh, acc[i][j], 0, 0, 0);
      }
    }
    __syncthreads();
  }
  // epilogue: C/D col=lane&15 (=r), row=kq*4+reg
#pragma unroll
  for (int j = 0; j < 4; ++j) {
    int gc = bn0 + (wn + j) * 16 + r;
    if constexpr (OUTMODE == 0) {
      float bv = bias ? bias[gc] : 0.f;
      float* dst = (gc < splitN) ? ((float*)O1 + gc) : ((float*)O2 + gc - splitN);
#pragma unroll
      for (int i = 0; i < 4; ++i) {
        int gr = bm0 + (wm + i) * 16 + kq * 4;
#pragma unroll
        for (int rr = 0; rr < 4; ++rr)
          dst[(size_t)(gr + rr) * ldc] = acc[i][j][rr] + bv;
      }
    } else {
      unsigned short* Chi = (unsigned short*)O1;
      unsigned short* Clo = (unsigned short*)O2;
#pragma unroll
      for (int i = 0; i < 4; ++i) {
        int gr = bm0 + (wm + i) * 16 + kq * 4;
#pragma unroll
        for (int rr = 0; rr < 4; ++rr) {
          float v = acc[i][j][rr];
          unsigned short hi = f32_to_bf16_rne(v);
          Chi[(size_t)(gr + rr) * ldc + gc] = hi;
          Clo[(size_t)(gr + rr) * ldc + gc] = f32_to_bf16_rne(v - bf16_to_f32(hi));
        }
      }
    }
  }
}

// ---- dt GEMM: dtv = softplus(xdbl[:,0:32] @ dt_w + dt_b), K=32 one-shot ----
// 128x128 tile, 4 waves (2x2 of 64x64), single staging phase, no K-loop.
// LDS linear [row][32] shorts: worst aliasing 2-way (free).
__global__ __launch_bounds__(256) void gemm_dt(
    const float* __restrict__ xdbl, const unsigned short* __restrict__ Bhi,
    const unsigned short* __restrict__ Blo, const float* __restrict__ dtb,
    float* __restrict__ dtv)
{
  __shared__ __align__(16) unsigned short lAhi[128 * 32];
  __shared__ __align__(16) unsigned short lAlo[128 * 32];
  __shared__ __align__(16) unsigned short lBhi[128 * 32];
  __shared__ __align__(16) unsigned short lBlo[128 * 32];
  const int tid = threadIdx.x, wave = tid >> 6, lane = tid & 63;
  const int r = lane & 15, kq = lane >> 4;
  const int bm0 = blockIdx.y * 128, bn0 = blockIdx.x * 128;
  const int wm = (wave >> 1) * 4, wn = (wave & 1) * 4;

  // stage A: 128 rows x 32 cols fp32 (stride XD) -> hi/lo split
  {
    const int row = tid >> 1, c0 = (tid & 1) * 16;
    const float* src = xdbl + (size_t)(bm0 + row) * XD + c0;
#pragma unroll
    for (int j = 0; j < 4; ++j) {
      float4 v = *(const float4*)(src + 4 * j);
      unsigned short h0 = f32_to_bf16_rne(v.x), h1 = f32_to_bf16_rne(v.y);
      unsigned short h2 = f32_to_bf16_rne(v.z), h3 = f32_to_bf16_rne(v.w);
      *(ushort4*)&lAhi[row * 32 + c0 + 4 * j] = make_ushort4(h0, h1, h2, h3);
      *(ushort4*)&lAlo[row * 32 + c0 + 4 * j] =
          make_ushort4(f32_to_bf16_rne(v.x - bf16_to_f32(h0)),
                       f32_to_bf16_rne(v.y - bf16_to_f32(h1)),
                       f32_to_bf16_rne(v.z - bf16_to_f32(h2)),
                       f32_to_bf16_rne(v.w - bf16_to_f32(h3)));
    }
    // stage B: dt_wT pair rows are 32-contiguous -> tile is contiguous 8 KB
    const uint4* sbh = (const uint4*)(Bhi + (size_t)bn0 * 32);
    const uint4* sbl = (const uint4*)(Blo + (size_t)bn0 * 32);
    ((uint4*)lBhi)[tid] = sbh[tid];
    ((uint4*)lBhi)[tid + 256] = sbh[tid + 256];
    ((uint4*)lBlo)[tid] = sbl[tid];
    ((uint4*)lBlo)[tid + 256] = sbl[tid + 256];
  }
  __syncthreads();

  f32x4 acc[4][4];
#pragma unroll
  for (int i = 0; i < 4; ++i)
#pragma unroll
    for (int j = 0; j < 4; ++j) acc[i][j] = 0.f;

  bf16x8 ah[4], al[4];
#pragma unroll
  for (int i = 0; i < 4; ++i) {
    int row = ((wm + i) * 16 + r) * 32 + kq * 8;
    ah[i] = *(const bf16x8*)&lAhi[row];
    al[i] = *(const bf16x8*)&lAlo[row];
  }
#pragma unroll
  for (int j = 0; j < 4; ++j) {
    int col = ((wn + j) * 16 + r) * 32 + kq * 8;
    bf16x8 bh = *(const bf16x8*)&lBhi[col];
    bf16x8 bl = *(const bf16x8*)&lBlo[col];
#pragma unroll
    for (int i = 0; i < 4; ++i) {
      acc[i][j] = __builtin_amdgcn_mfma_f32_16x16x32_bf16(ah[i], bh, acc[i][j], 0, 0, 0);
      acc[i][j] = __builtin_amdgcn_mfma_f32_16x16x32_bf16(ah[i], bl, acc[i][j], 0, 0, 0);
      acc[i][j] = __builtin_amdgcn_mfma_f32_16x16x32_bf16(al[i], bh, acc[i][j], 0, 0, 0);
    }
  }
  // epilogue: bias + softplus fused
#pragma unroll
  for (int j = 0; j < 4; ++j) {
    int gc = bn0 + (wn + j) * 16 + r;
    float bv = dtb[gc];
#pragma unroll
    for (int i = 0; i < 4; ++i) {
      int gr = bm0 + (wm + i) * 16 + kq * 4;
#pragma unroll
      for (int rr = 0; rr < 4; ++rr) {
        float a = acc[i][j][rr] + bv;
        float t = fexp2(-fabsf(a) * L2E);
        dtv[(size_t)(gr + rr) * DI + gc] =
            fmaxf(a, 0.f) + flog2(1.f + t) * LN2;
      }
    }
  }
}

// ---- xproj split-K: A fp32 on-the-fly, 64x64 tile, atomics into xdbl -------
__global__ __launch_bounds__(256) void gemm_splitk(
    const float* __restrict__ A, const unsigned short* __restrict__ Bhi,
    const unsigned short* __restrict__ Blo, float* __restrict__ Cacc,
    int M, int N, int K, int kslice)
{
  constexpr int BM = 64, BN = 64, PAD = 40;
  __shared__ unsigned short lAhi[BM * PAD];
  __shared__ unsigned short lAlo[BM * PAD];
  __shared__ unsigned short lBhi[BN * PAD];
  __shared__ unsigned short lBlo[BN * PAD];
  const int tid  = threadIdx.x;
  const int wave = tid >> 6, lane = tid & 63;
  const int wm0 = (wave >> 1) * 32, wn0 = (wave & 1) * 32;
  const int bm0 = blockIdx.y * BM, bn0 = blockIdx.x * BN;
  const int kz  = blockIdx.z;
  const int sr = tid >> 3, sc = (tid & 7) << 2;
  const int fm = lane & 15, fq = lane >> 4;

  f32x4 acc[2][2];
#pragma unroll
  for (int i = 0; i < 2; ++i)
#pragma unroll
    for (int j = 0; j < 2; ++j) acc[i][j] = 0.f;

  const int kbeg = kz * kslice, kend = kbeg + kslice;
  for (int k0 = kbeg; k0 < kend; k0 += 32) {
#pragma unroll
    for (int r = sr; r < BM; r += 32) {
      float4 v = *(const float4*)(A + (size_t)(bm0 + r) * K + k0 + sc);
      unsigned short h0 = f32_to_bf16_rne(v.x), h1 = f32_to_bf16_rne(v.y);
      unsigned short h2 = f32_to_bf16_rne(v.z), h3 = f32_to_bf16_rne(v.w);
      *(ushort4*)&lAhi[r * PAD + sc] = make_ushort4(h0, h1, h2, h3);
      *(ushort4*)&lAlo[r * PAD + sc] =
          make_ushort4(f32_to_bf16_rne(v.x - bf16_to_f32(h0)),
                       f32_to_bf16_rne(v.y - bf16_to_f32(h1)),
                       f32_to_bf16_rne(v.z - bf16_to_f32(h2)),
                       f32_to_bf16_rne(v.w - bf16_to_f32(h3)));
    }
#pragma unroll
    for (int r = sr; r < BN; r += 32) {
      *(ushort4*)&lBhi[r * PAD + sc] =
          *(const ushort4*)(Bhi + (size_t)(bn0 + r) * K + k0 + sc);
      *(ushort4*)&lBlo[r * PAD + sc] =
          *(const ushort4*)(Blo + (size_t)(bn0 + r) * K + k0 + sc);
    }
    __syncthreads();
    bf16x8 ah[2], al[2];
#pragma unroll
    for (int i = 0; i < 2; ++i) {
      int row = wm0 + i * 16 + fm;
      ah[i] = *(const bf16x8*)&lAhi[row * PAD + fq * 8];
      al[i] = *(const bf16x8*)&lAlo[row * PAD + fq * 8];
    }
#pragma unroll
    for (int j = 0; j < 2; ++j) {
      int col = wn0 + j * 16 + fm;
      bf16x8 bh = *(const bf16x8*)&lBhi[col * PAD + fq * 8];
      bf16x8 bl = *(const bf16x8*)&lBlo[col * PAD + fq * 8];
#pragma unroll
      for (int i = 0; i < 2; ++i) {
        acc[i][j] = __builtin_amdgcn_mfma_f32_16x16x32_bf16(ah[i], bh, acc[i][j], 0, 0, 0);
        acc[i][j] = __builtin_amdgcn_mfma_f32_16x16x32_bf16(ah[i], bl, acc[i][j], 0, 0, 0);
        acc[i][j] = __builtin_amdgcn_mfma_f32_16x16x32_bf16(al[i], bh, acc[i][j], 0, 0, 0);
      }
    }
    __syncthreads();
  }
#pragma unroll
  for (int j = 0; j < 2; ++j) {
    int gc = bn0 + wn0 + j * 16 + fm;
#pragma unroll
    for (int i = 0; i < 2; ++i) {
      int gr = bm0 + wm0 + i * 16 + fq * 4;
#pragma unroll
      for (int rr = 0; rr < 4; ++rr)
        atomicAdd(&Cacc[(size_t)(gr + rr) * N + gc], acc[i][j][rr]);
    }
  }
}

// ---------------- depthwise causal conv1d (4 taps) + silu --------------------
__global__ __launch_bounds__(256) void conv_silu(
    const float* __restrict__ u, const float* __restrict__ cw,
    const float* __restrict__ cb, float* __restrict__ uc)
{
  int idx = blockIdx.x * 256 + threadIdx.x;
  int e = idx & (DI - 1);
  int m = idx >> 10;
  int t = m & (L_ - 1);
  const float* w = cw + e * 4;
  float acc = cb[e];
#pragma unroll
  for (int k = 0; k < 4; ++k) {
    int tt = t - 3 + k;
    if (tt >= 0) acc += u[(size_t)(m - 3 + k) * DI + e] * w[k];
  }
  uc[idx] = acc * fsigmoid(acc);
}

// ---------------- fused scan: local scan + S_loc + (P,H,G) per chunk ---------
__global__ __launch_bounds__(256) void scan_fused(
    const float* __restrict__ dtv, const float* __restrict__ uc,
    const float* __restrict__ xdbl, const float* __restrict__ A_log,
    const float* __restrict__ z, const float* __restrict__ Dsk,
    float* __restrict__ Pbuf, float* __restrict__ Hbuf,
    float* __restrict__ Gbuf, float* __restrict__ sacc)
{
  const int l = threadIdx.x & 63;
  const int s = threadIdx.x >> 6;
  const int chan = blockIdx.x * 64 + l;
  const int e = chan & (DI - 1);
  const int b = chan >> 10;
  const int chunk = blockIdx.y;

  float Aef[4];
#pragma unroll
  for (int j = 0; j < 4; ++j)
    Aef[j] = -__expf(A_log[e * NS + s * 4 + j]) * L2E;
  const float Dv = (s == 0) ? Dsk[e] : 0.f;

  size_t m0 = (size_t)b * L_ + (size_t)chunk * TCH;
  const float* pd = dtv + m0 * DI + e;
  const float* pu = uc  + m0 * DI + e;
  const float* pz = z   + m0 * DI + e;
  const float* px = xdbl + m0 * XD + RK + s * 4;

  float h[4] = {0.f, 0.f, 0.f, 0.f};
  float cp[4] = {1.f, 1.f, 1.f, 1.f};
  float g[4] = {0.f, 0.f, 0.f, 0.f};
  float ssum = 0.f, asum = 0.f;

  for (int t = 0; t < TCH; ++t) {
    float a  = *pd;
    float uu = *pu;
    float zz = *pz;
    float4 bv = *(const float4*)px;
    float4 cv = *(const float4*)(px + NS);
    float gate = zz * fsigmoid(zz);
    float du = a * uu;
    asum += a;
    float bb[4] = {bv.x, bv.y, bv.z, bv.w};
    float cc[4] = {cv.x, cv.y, cv.z, cv.w};
    float y = 0.f;
#pragma unroll
    for (int j = 0; j < 4; ++j) {
      float dA = fexp2(a * Aef[j]);
      h[j] = fmaf(dA, h[j], du * bb[j]);
      cp[j] *= dA;
      g[j] = fmaf(gate * cp[j], cc[j], g[j]);
      y = fmaf(h[j], cc[j], y);
    }
    ssum = fmaf(gate, fmaf(uu, Dv, y), ssum);
    pd += DI; pu += DI; pz += DI; px += XD;
  }

  size_t base = ((size_t)chunk * NS + s * 4) * NCHAN + chan;
#pragma unroll
  for (int j = 0; j < 4; ++j) {
    Pbuf[base + (size_t)j * NCHAN] = fexp2(Aef[j] * asum);
    Hbuf[base + (size_t)j * NCHAN] = h[j];
    Gbuf[base + (size_t)j * NCHAN] = g[j];
  }
  atomicAdd(&sacc[chan], ssum);
}

// ---------------- compose: 1 thread per (chan,state) -------------------------
__global__ __launch_bounds__(256) void scan_compose(
    const float* __restrict__ Pbuf, const float* __restrict__ Hbuf,
    const float* __restrict__ Gbuf, float* __restrict__ sacc)
{
  int idx = blockIdx.x * 256 + threadIdx.x;   // NCHAN*NS threads
  int chan = idx & (NCHAN - 1);
  int n = idx >> 12;
  float h0 = 0.f, acc = 0.f;
  size_t o = (size_t)n * NCHAN + chan;
  const size_t step = (size_t)NS * NCHAN;
  for (int c = 0; c < NCH; ++c, o += step) {
    acc = fmaf(Gbuf[o], h0, acc);
    h0 = fmaf(Pbuf[o], h0, Hbuf[o]);
  }
  atomicAdd(&sacc[chan], acc);
}

// ---------------- out_proj: split-E, atomicAdd into zeroed out ---------------
__global__ __launch_bounds__(64) void out_proj_k(
    const float* __restrict__ s, const float* __restrict__ ow,
    float* __restrict__ out)
{
  int d = blockIdx.x * 64 + threadIdx.x;
  int b = blockIdx.y;
  int e0 = blockIdx.z * 128;
  const float* sb = s + b * DI;
  float acc = 0.f;
  for (int e = e0; e < e0 + 128; ++e)
    acc = fmaf(sb[e], ow[(size_t)e * DM + d], acc);
  atomicAdd(&out[b * DM + d], acc * (1.f / (float)L_));
}

extern "C" void kernel_launch(void* const* d_in, const int* in_sizes, int n_in,
                              void* d_out, int out_size, void* d_ws, size_t ws_size,
                              hipStream_t stream)
{
  const float* x      = (const float*)d_in[0];
  const float* w_proj = (const float*)d_in[1];
  const float* b_proj = (const float*)d_in[2];
  const float* in_w   = (const float*)d_in[3];
  const float* conv_w = (const float*)d_in[4];
  const float* conv_b = (const float*)d_in[5];
  const float* xproj_w= (const float*)d_in[6];
  const float* dt_w   = (const float*)d_in[7];
  const float* dt_b   = (const float*)d_in[8];
  const float* A_log  = (const float*)d_in[9];
  const float* D_skip = (const float*)d_in[10];
  const float* out_w  = (const float*)d_in[11];

  // Workspace (~238 MB): bufA: u -> dtv; bufZ: z; bufC: x-pair -> uc.
  float* ws   = (float*)d_ws;
  float* bufA = ws;
  float* bufZ = bufA + (size_t)M_ * DI;
  float* bufC = bufZ + (size_t)M_ * DI;
  float* xdbl = bufC + (size_t)M_ * DI;              // M*64
  float* Pb   = xdbl + (size_t)M_ * XD;
  float* Hb   = Pb   + (size_t)NCH * NS * NCHAN;
  float* Gb   = Hb   + (size_t)NCH * NS * NCHAN;
  float* sacc = Gb   + (size_t)NCH * NS * NCHAN;     // 4096 f
  unsigned short* inT_hi = (unsigned short*)(sacc + NCHAN);  // [2048][512]
  unsigned short* inT_lo = inT_hi + (size_t)2 * DI * DM;
  unsigned short* wp_hi  = inT_lo + (size_t)2 * DI * DM;     // [256][512]
  unsigned short* wp_lo  = wp_hi  + (size_t)DIN * DM;
  unsigned short* w12_hi = wp_lo  + (size_t)DIN * DM;        // [2048][256]
  unsigned short* w12_lo = w12_hi + (size_t)2 * DI * DIN;
  unsigned short* xpT_hi = w12_lo + (size_t)2 * DI * DIN;    // [64][1024]
  unsigned short* xpT_lo = xpT_hi + (size_t)XD * DI;
  unsigned short* dtT_hi = xpT_lo + (size_t)XD * DI;         // [1024][32]
  unsigned short* dtT_lo = dtT_hi + (size_t)DI * RK;
  float* bias2 = (float*)(dtT_lo + (size_t)DI * RK);         // [2048]

  unsigned short* x_hi = (unsigned short*)bufC;      // [M][256] pair
  unsigned short* x_lo = x_hi + (size_t)M_ * DIN;
  float* u    = bufA;
  float* z    = bufZ;
  float* uc   = bufC;                                // overwrites x-pair (dead)
  float* dtv  = bufA;                                // overwrites u (dead)

  // 0. weight prep
  transpose_split<<<dim3(DM / 32, 2 * DI / 32), 256, 0, stream>>>(
      in_w, DM, 2 * DI, inT_hi, inT_lo);
  transpose_split<<<dim3(DI / 32, XD / 32), 256, 0, stream>>>(
      xproj_w, DI, XD, xpT_hi, xpT_lo);
  transpose_split<<<dim3(RK / 32, DI / 32), 256, 0, stream>>>(
      dt_w, RK, DI, dtT_hi, dtT_lo);
  split_pair<<<(DIN * DM / 4 + 255) / 256, 256, 0, stream>>>(
      w_proj, wp_hi, wp_lo, DIN * DM / 4);
  split_pair<<<(M_ * DIN / 4 + 255) / 256, 256, 0, stream>>>(
      x, x_hi, x_lo, M_ * DIN / 4);
  // 0b. W12T[2048][256] = inT @ w_proj  (= (W1@W2)^T), bf16-pair output
  gemm_ps3<1><<<dim3(DIN / 128, 2 * DI / 128), 256, 0, stream>>>(
      inT_hi, inT_lo, wp_hi, wp_lo, nullptr, w12_hi, w12_lo,
      2 * DI, DIN, DM, DIN, DIN);
  // 0c. bias2 = b_proj @ in_w
  bias2_k<<<2 * DI / 256, 256, 0, stream>>>(b_proj, in_w, bias2);

  // 1. (u|z) = x @ W12 + bias2  (fused input_proj+in_proj)  [M,2048]
  gemm_ps3<0><<<dim3(2 * DI / 128, M_ / 128), 256, 0, stream>>>(
      x_hi, x_lo, w12_hi, w12_lo, bias2, u, z, M_, 2 * DI, DIN, DI, DI);
  // 2. uc = silu(causal_dwconv(u) + conv_b)   (overwrites x-pair; dead)
  conv_silu<<<(M_ * DI) / 256, 256, 0, stream>>>(u, conv_w, conv_b, uc);
  // 3. xdbl = uc @ xproj_w, split-K=4 atomics  [M, 64]
  hipMemsetAsync(xdbl, 0, (size_t)M_ * XD * sizeof(float), stream);
  gemm_splitk<<<dim3(1, M_ / 64, 4), 256, 0, stream>>>(
      uc, xpT_hi, xpT_lo, xdbl, M_, XD, DI, DI / 4);
  // 4. dtv = softplus(xdbl[:,0:32] @ dt_w + dt_b)  — one-shot MFMA GEMM
  gemm_dt<<<dim3(DI / 128, M_ / 128), 256, 0, stream>>>(
      xdbl, dtT_hi, dtT_lo, dt_b, dtv);
  // 5. fused single-pass chunked scan
  hipMemsetAsync(sacc, 0, NCHAN * sizeof(float), stream);
  scan_fused<<<dim3(NCHAN / 64, NCH), 256, 0, stream>>>(
      dtv, uc, xdbl, A_log, z, D_skip, Pb, Hb, Gb, sacc);
  // 6. compose boundaries + corrections
  scan_compose<<<(NCHAN * NS) / 256, 256, 0, stream>>>(Pb, Hb, Gb, sacc);
  // 7. out = (s/L) @ out_w
  hipMemsetAsync(d_out, 0, (size_t)out_size * sizeof(float), stream);
  out_proj_k<<<dim3(DM / 64, B_, DI / 128), 64, 0, stream>>>(
      sacc, out_w, (float*)d_out);
}